// Round 3
// baseline (1278.428 us; speedup 1.0000x reference)
//
#include <hip/hip_runtime.h>
#include <hip/hip_bf16.h>

// WorkflowGNN: GCN(32->64)+ReLU, GAT(64->64,h=1)+ReLU, GCN(64->64)+ReLU,
// heads: opt [N,10], bottleneck [N,1], mean-embed [64].
// Inputs float32, OUTPUT float32 (reference dtype; round-2 bf16-write aliasing
// produced the 0.62 absmax signature of sigmoids landing in the opt region).
// Strategy: bucketed inverse-adjacency (CAP=64 slots/node, self-loop preseeded),
// gather-based aggregation (wave per node, lane = feature), no float atomics.

#define CAP 64

// cnt[v]=1 (self-loop), adj[v][0]=v
__global__ void k_init(int* __restrict__ cnt, int* __restrict__ adj, int n){
  int v = blockIdx.x*blockDim.x + threadIdx.x;
  if (v < n){ cnt[v] = 1; adj[(size_t)v*CAP] = v; }
}

// histogram+fill: for each edge, append src to dst's bucket
__global__ void k_hist(const int* __restrict__ src, const int* __restrict__ dst,
                       int* __restrict__ cnt, int* __restrict__ adj, int e){
  int i = blockIdx.x*blockDim.x + threadIdx.x;
  if (i < e){
    int d = dst[i];
    int pos = atomicAdd(&cnt[d], 1);
    if (pos < CAP) adj[(size_t)d*CAP + pos] = src[i];
  }
}

__global__ void k_dinv(const int* __restrict__ cnt, float* __restrict__ dinv, int n){
  int v = blockIdx.x*blockDim.x + threadIdx.x;
  if (v < n) dinv[v] = rsqrtf((float)cnt[v]);   // cnt >= 1 always (self-loop)
}

// t[v][f] = sum_k x[v][k] * W[k][f]   (W f32 [K,64] staged in LDS)
template<int K>
__global__ void k_gemm(const float* __restrict__ x, const float* __restrict__ W,
                       float* __restrict__ t, int n){
  __shared__ float Wl[K*64];
  int tid = threadIdx.x;
  for (int i = tid; i < K*64; i += 256) Wl[i] = W[i];
  __syncthreads();
  int v = blockIdx.x*4 + (tid >> 6);
  int lane = tid & 63;
  if (v >= n) return;
  const float* xr = x + (size_t)v*K;
  float acc = 0.f;
  #pragma unroll
  for (int k = 0; k < K; k++)
    acc = fmaf(xr[k], Wl[k*64 + lane], acc);
  t[(size_t)v*64 + lane] = acc;
}

// GEMM (K=64) + fused alpha_src/alpha_dst per-node dots (wave shuffle reduce)
__global__ void k_gemm_alpha(const float* __restrict__ x, const float* __restrict__ W,
                             const float* __restrict__ asrc, const float* __restrict__ adst,
                             float* __restrict__ t, float* __restrict__ als, float* __restrict__ ald, int n){
  __shared__ float Wl[64*64];
  __shared__ float asl[64], adl[64];
  int tid = threadIdx.x;
  for (int i = tid; i < 64*64; i += 256) Wl[i] = W[i];
  if (tid < 64){ asl[tid] = asrc[tid]; adl[tid] = adst[tid]; }
  __syncthreads();
  int v = blockIdx.x*4 + (tid >> 6);
  int lane = tid & 63;
  if (v >= n) return;
  const float* xr = x + (size_t)v*64;
  float acc = 0.f;
  #pragma unroll
  for (int k = 0; k < 64; k++)
    acc = fmaf(xr[k], Wl[k*64 + lane], acc);
  t[(size_t)v*64 + lane] = acc;
  float s1 = acc * asl[lane];
  float s2 = acc * adl[lane];
  #pragma unroll
  for (int off = 32; off; off >>= 1){
    s1 += __shfl_xor(s1, off);
    s2 += __shfl_xor(s2, off);
  }
  if (lane == 0){ als[v] = s1; ald[v] = s2; }
}

// h[v][f] = relu( dinv[v] * sum_{u in adj[v]} dinv[u]*t[u][f]  + b[f] )
__global__ void k_gcn_agg(const float* __restrict__ t, const int* __restrict__ adj,
                          const int* __restrict__ cnt, const float* __restrict__ dinv,
                          const float* __restrict__ b, float* __restrict__ h, int n){
  __shared__ float bl[64];
  int tid = threadIdx.x;
  if (tid < 64) bl[tid] = b[tid];
  __syncthreads();
  int v = blockIdx.x*4 + (tid >> 6);
  int lane = tid & 63;
  if (v >= n) return;
  int c = min(cnt[v], CAP);
  const int* row = adj + (size_t)v*CAP;
  float acc = 0.f;
  for (int j = 0; j < c; j++){
    int u = row[j];                                    // broadcast load
    acc = fmaf(dinv[u], t[(size_t)u*64 + lane], acc);  // coalesced row gather
  }
  float r = fmaf(acc, dinv[v], bl[lane]);
  h[(size_t)v*64 + lane] = fmaxf(r, 0.f);
}

// GAT aggregation: per-dst softmax over incoming edges, weighted sum of g rows
__global__ void k_gat_agg(const float* __restrict__ g, const int* __restrict__ adj,
                          const int* __restrict__ cnt, const float* __restrict__ als,
                          const float* __restrict__ ald, const float* __restrict__ b,
                          float* __restrict__ h, int n){
  __shared__ float bl[64];
  int tid = threadIdx.x;
  if (tid < 64) bl[tid] = b[tid];
  __syncthreads();
  int v = blockIdx.x*4 + (tid >> 6);
  int lane = tid & 63;
  if (v >= n) return;
  int c = min(cnt[v], CAP);
  const int* row = adj + (size_t)v*CAP;
  float adv = ald[v];
  // pass 1: max over edges (lanes split edges; c<=64 so <=1 iter/lane)
  float lm = -1e30f;
  for (int j = lane; j < c; j += 64){
    int u = row[j];
    float ev = als[u] + adv;
    ev = ev > 0.f ? ev : 0.2f*ev;
    lm = fmaxf(lm, ev);
  }
  #pragma unroll
  for (int off = 32; off; off >>= 1) lm = fmaxf(lm, __shfl_xor(lm, off));
  // pass 2: sum exp(e - m)
  float ls = 0.f;
  for (int j = lane; j < c; j += 64){
    int u = row[j];
    float ev = als[u] + adv;
    ev = ev > 0.f ? ev : 0.2f*ev;
    ls += __expf(ev - lm);
  }
  #pragma unroll
  for (int off = 32; off; off >>= 1) ls += __shfl_xor(ls, off);
  float inv = 1.f / ls;
  // pass 3: weighted accumulate (lane = feature)
  float acc = 0.f;
  for (int j = 0; j < c; j++){
    int u = row[j];
    float ev = als[u] + adv;
    ev = ev > 0.f ? ev : 0.2f*ev;
    float w = __expf(ev - lm);
    acc = fmaf(w, g[(size_t)u*64 + lane], acc);
  }
  h[(size_t)v*64 + lane] = fmaxf(fmaf(acc, inv, bl[lane]), 0.f);
}

// heads: opt [N,10], bottleneck [N], per-block partial feature-sum for mean-embed
__global__ void k_heads(const float* __restrict__ h,
                        const float* __restrict__ Wopt, const float* __restrict__ bopt,
                        const float* __restrict__ Wb1, const float* __restrict__ bb1,
                        const float* __restrict__ Wb2, const float* __restrict__ bb2,
                        float* __restrict__ out_opt, float* __restrict__ out_bot,
                        float* __restrict__ partial, int n){
  __shared__ float Woptl[640], Wb1l[2048], boptl[10], bb1l[32], Wb2l[32];
  __shared__ float bb2s;
  __shared__ float red[256];
  int tid = threadIdx.x;
  for (int i = tid; i < 640;  i += 256) Woptl[i] = Wopt[i];
  for (int i = tid; i < 2048; i += 256) Wb1l[i]  = Wb1[i];
  if (tid < 10) boptl[tid] = bopt[tid];
  if (tid >= 64 && tid < 96) bb1l[tid-64] = bb1[tid-64];
  if (tid >= 128 && tid < 160) Wb2l[tid-128] = Wb2[tid-128];
  if (tid == 192) bb2s = bb2[0];
  __syncthreads();
  int wave = tid >> 6, lane = tid & 63;
  int oc = lane < 10 ? lane : 0;
  int j  = lane & 31;
  float gacc = 0.f;
  for (int v0 = blockIdx.x*4; v0 < n; v0 += gridDim.x*4){
    int v = v0 + wave;
    if (v < n){                                  // wave-uniform (n % 4 == 0)
      float hv = h[(size_t)v*64 + lane];
      gacc += hv;
      float a_opt = boptl[oc];
      float a_z1  = bb1l[j];
      #pragma unroll
      for (int f = 0; f < 64; f++){
        float hf = __shfl(hv, f);
        a_opt = fmaf(hf, Woptl[f*10 + oc], a_opt);
        a_z1  = fmaf(hf, Wb1l[f*32 + j],  a_z1);
      }
      if (lane < 10) out_opt[(size_t)v*10 + lane] = a_opt;
      float z1 = fmaxf(a_z1, 0.f);
      float contrib = (lane < 32) ? z1 * Wb2l[j] : 0.f;
      #pragma unroll
      for (int off = 32; off; off >>= 1) contrib += __shfl_xor(contrib, off);
      if (lane == 0){
        float z2 = contrib + bb2s;
        out_bot[v] = 1.f / (1.f + __expf(-z2));
      }
    }
  }
  red[tid] = gacc;
  __syncthreads();
  if (tid < 64)
    partial[(size_t)blockIdx.x*64 + tid] = red[tid] + red[64+tid] + red[128+tid] + red[192+tid];
}

__global__ void k_embed(const float* __restrict__ partial, float* __restrict__ out_emb,
                        int nb, float invn){
  __shared__ float red[256];
  int tid = threadIdx.x;
  int lane = tid & 63, q = tid >> 6;
  float s = 0.f;
  for (int b = q; b < nb; b += 4) s += partial[(size_t)b*64 + lane];
  red[tid] = s;
  __syncthreads();
  if (tid < 64)
    out_emb[tid] = (red[tid] + red[64+tid] + red[128+tid] + red[192+tid]) * invn;
}

extern "C" void kernel_launch(void* const* d_in, const int* in_sizes, int n_in,
                              void* d_out, int out_size, void* d_ws, size_t ws_size,
                              hipStream_t stream) {
  const float* x    = (const float*)d_in[0];
  const int*   ei   = (const int*)d_in[1];
  const float* W1   = (const float*)d_in[2];
  const float* b1   = (const float*)d_in[3];
  const float* W2   = (const float*)d_in[4];
  const float* a_s  = (const float*)d_in[5];
  const float* a_d  = (const float*)d_in[6];
  const float* b2   = (const float*)d_in[7];
  const float* W3   = (const float*)d_in[8];
  const float* b3   = (const float*)d_in[9];
  const float* Wopt = (const float*)d_in[10];
  const float* bopt = (const float*)d_in[11];
  const float* Wb1  = (const float*)d_in[12];
  const float* bb1  = (const float*)d_in[13];
  const float* Wb2  = (const float*)d_in[14];
  const float* bb2  = (const float*)d_in[15];

  int n = in_sizes[0] / 32;      // 100000
  int e = in_sizes[1] / 2;       // 1250000
  const int* src = ei;
  const int* dst = ei + e;

  // workspace bump allocator (256B aligned); total ~78.6 MB
  char* ws = (char*)d_ws;
  size_t off = 0;
  auto alloc = [&](size_t bytes) -> void* {
    void* p = ws + off;
    off += (bytes + 255) & ~(size_t)255;
    return p;
  };
  int*   cnt     = (int*)  alloc((size_t)n * 4);
  int*   adj     = (int*)  alloc((size_t)n * CAP * 4);
  float* dinv    = (float*)alloc((size_t)n * 4);
  float* als     = (float*)alloc((size_t)n * 4);
  float* ald     = (float*)alloc((size_t)n * 4);
  float* tbuf    = (float*)alloc((size_t)n * 64 * 4);
  float* hbuf    = (float*)alloc((size_t)n * 64 * 4);
  float* partial = (float*)alloc((size_t)500 * 64 * 4);

  float* out_opt = (float*)d_out;
  float* out_bot = out_opt + (size_t)n * 10;
  float* out_emb = out_bot + n;

  int nbN  = (n + 255) / 256;
  int nbE  = (e + 255) / 256;
  int nb4  = (n + 3) / 4;

  k_init<<<nbN, 256, 0, stream>>>(cnt, adj, n);
  k_hist<<<nbE, 256, 0, stream>>>(src, dst, cnt, adj, e);
  k_dinv<<<nbN, 256, 0, stream>>>(cnt, dinv, n);

  // layer 1: GCN(32->64)
  k_gemm<32><<<nb4, 256, 0, stream>>>(x, W1, tbuf, n);
  k_gcn_agg<<<nb4, 256, 0, stream>>>(tbuf, adj, cnt, dinv, b1, hbuf, n);

  // layer 2: GAT(64->64)
  k_gemm_alpha<<<nb4, 256, 0, stream>>>(hbuf, W2, a_s, a_d, tbuf, als, ald, n);
  k_gat_agg<<<nb4, 256, 0, stream>>>(tbuf, adj, cnt, als, ald, b2, hbuf, n);

  // layer 3: GCN(64->64)
  k_gemm<64><<<nb4, 256, 0, stream>>>(hbuf, W3, tbuf, n);
  k_gcn_agg<<<nb4, 256, 0, stream>>>(tbuf, adj, cnt, dinv, b3, hbuf, n);

  // heads + mean embedding
  k_heads<<<500, 256, 0, stream>>>(hbuf, Wopt, bopt, Wb1, bb1, Wb2, bb2,
                                   out_opt, out_bot, partial, n);
  k_embed<<<1, 256, 0, stream>>>(partial, out_emb, 500, 1.0f / (float)n);
}

// Round 4
// 969.854 us; speedup vs baseline: 1.3182x; 1.3182x over previous
//
#include <hip/hip_runtime.h>
#include <hip/hip_bf16.h>

// WorkflowGNN: GCN(32->64)+ReLU, GAT(64->64,h=1)+ReLU, GCN(64->64)+ReLU,
// heads: opt [N,10], bottleneck [N,1], mean-embed [64]. f32 in/out.
// R3->R4: k_heads was 466us (36%): 500 blocks => 21% occupancy + 64-step
// serial bpermute chain per node. Rewritten as LDS mini-GEMM (16 nodes/block,
// 6250 blocks); mean-embed split into its own BW-bound kernel.

#define CAP 64

// cnt[v]=1 (self-loop), adj[v][0]=v
__global__ void k_init(int* __restrict__ cnt, int* __restrict__ adj, int n){
  int v = blockIdx.x*blockDim.x + threadIdx.x;
  if (v < n){ cnt[v] = 1; adj[(size_t)v*CAP] = v; }
}

// histogram+fill: for each edge, append src to dst's bucket
__global__ void k_hist(const int* __restrict__ src, const int* __restrict__ dst,
                       int* __restrict__ cnt, int* __restrict__ adj, int e){
  int i = blockIdx.x*blockDim.x + threadIdx.x;
  if (i < e){
    int d = dst[i];
    int pos = atomicAdd(&cnt[d], 1);
    if (pos < CAP) adj[(size_t)d*CAP + pos] = src[i];
  }
}

__global__ void k_dinv(const int* __restrict__ cnt, float* __restrict__ dinv, int n){
  int v = blockIdx.x*blockDim.x + threadIdx.x;
  if (v < n) dinv[v] = rsqrtf((float)cnt[v]);   // cnt >= 1 always (self-loop)
}

// t[v][f] = sum_k x[v][k] * W[k][f]   (W f32 [K,64] staged in LDS)
template<int K>
__global__ void k_gemm(const float* __restrict__ x, const float* __restrict__ W,
                       float* __restrict__ t, int n){
  __shared__ float Wl[K*64];
  int tid = threadIdx.x;
  for (int i = tid; i < K*64; i += 256) Wl[i] = W[i];
  __syncthreads();
  int v = blockIdx.x*4 + (tid >> 6);
  int lane = tid & 63;
  if (v >= n) return;
  const float* xr = x + (size_t)v*K;
  float acc = 0.f;
  #pragma unroll
  for (int k = 0; k < K; k++)
    acc = fmaf(xr[k], Wl[k*64 + lane], acc);
  t[(size_t)v*64 + lane] = acc;
}

// GEMM (K=64) + fused alpha_src/alpha_dst per-node dots (wave shuffle reduce)
__global__ void k_gemm_alpha(const float* __restrict__ x, const float* __restrict__ W,
                             const float* __restrict__ asrc, const float* __restrict__ adst,
                             float* __restrict__ t, float* __restrict__ als, float* __restrict__ ald, int n){
  __shared__ float Wl[64*64];
  __shared__ float asl[64], adl[64];
  int tid = threadIdx.x;
  for (int i = tid; i < 64*64; i += 256) Wl[i] = W[i];
  if (tid < 64){ asl[tid] = asrc[tid]; adl[tid] = adst[tid]; }
  __syncthreads();
  int v = blockIdx.x*4 + (tid >> 6);
  int lane = tid & 63;
  if (v >= n) return;
  const float* xr = x + (size_t)v*64;
  float acc = 0.f;
  #pragma unroll
  for (int k = 0; k < 64; k++)
    acc = fmaf(xr[k], Wl[k*64 + lane], acc);
  t[(size_t)v*64 + lane] = acc;
  float s1 = acc * asl[lane];
  float s2 = acc * adl[lane];
  #pragma unroll
  for (int off = 32; off; off >>= 1){
    s1 += __shfl_xor(s1, off);
    s2 += __shfl_xor(s2, off);
  }
  if (lane == 0){ als[v] = s1; ald[v] = s2; }
}

// h[v][f] = relu( dinv[v] * sum_{u in adj[v]} dinv[u]*t[u][f]  + b[f] )
__global__ void k_gcn_agg(const float* __restrict__ t, const int* __restrict__ adj,
                          const int* __restrict__ cnt, const float* __restrict__ dinv,
                          const float* __restrict__ b, float* __restrict__ h, int n){
  __shared__ float bl[64];
  int tid = threadIdx.x;
  if (tid < 64) bl[tid] = b[tid];
  __syncthreads();
  int v = blockIdx.x*4 + (tid >> 6);
  int lane = tid & 63;
  if (v >= n) return;
  int c = min(cnt[v], CAP);
  const int* row = adj + (size_t)v*CAP;
  float acc = 0.f;
  for (int j = 0; j < c; j++){
    int u = row[j];                                    // broadcast load
    acc = fmaf(dinv[u], t[(size_t)u*64 + lane], acc);  // coalesced row gather
  }
  float r = fmaf(acc, dinv[v], bl[lane]);
  h[(size_t)v*64 + lane] = fmaxf(r, 0.f);
}

// GAT aggregation: per-dst softmax over incoming edges, weighted sum of g rows
__global__ void k_gat_agg(const float* __restrict__ g, const int* __restrict__ adj,
                          const int* __restrict__ cnt, const float* __restrict__ als,
                          const float* __restrict__ ald, const float* __restrict__ b,
                          float* __restrict__ h, int n){
  __shared__ float bl[64];
  int tid = threadIdx.x;
  if (tid < 64) bl[tid] = b[tid];
  __syncthreads();
  int v = blockIdx.x*4 + (tid >> 6);
  int lane = tid & 63;
  if (v >= n) return;
  int c = min(cnt[v], CAP);
  const int* row = adj + (size_t)v*CAP;
  float adv = ald[v];
  // pass 1: max over edges (lanes split edges; c<=64 so <=1 iter/lane)
  float lm = -1e30f;
  for (int j = lane; j < c; j += 64){
    int u = row[j];
    float ev = als[u] + adv;
    ev = ev > 0.f ? ev : 0.2f*ev;
    lm = fmaxf(lm, ev);
  }
  #pragma unroll
  for (int off = 32; off; off >>= 1) lm = fmaxf(lm, __shfl_xor(lm, off));
  // pass 2: sum exp(e - m)
  float ls = 0.f;
  for (int j = lane; j < c; j += 64){
    int u = row[j];
    float ev = als[u] + adv;
    ev = ev > 0.f ? ev : 0.2f*ev;
    ls += __expf(ev - lm);
  }
  #pragma unroll
  for (int off = 32; off; off >>= 1) ls += __shfl_xor(ls, off);
  float inv = 1.f / ls;
  // pass 3: weighted accumulate (lane = feature)
  float acc = 0.f;
  for (int j = 0; j < c; j++){
    int u = row[j];
    float ev = als[u] + adv;
    ev = ev > 0.f ? ev : 0.2f*ev;
    float w = __expf(ev - lm);
    acc = fmaf(w, g[(size_t)u*64 + lane], acc);
  }
  h[(size_t)v*64 + lane] = fmaxf(fmaf(acc, inv, bl[lane]), 0.f);
}

// heads as LDS mini-GEMM: out[N,{10 opt | 32 bb1-cols}] = h @ Wcat.
// 16 nodes/block (grid 6250), wave handles 4 nodes, lane = output column:
// cols 0..9 -> opt, cols 32..63 -> bottleneck hidden (z1), others idle.
__global__ __launch_bounds__(256) void k_heads(const float* __restrict__ h,
                        const float* __restrict__ Wopt, const float* __restrict__ bopt,
                        const float* __restrict__ Wb1, const float* __restrict__ bb1,
                        const float* __restrict__ Wb2, const float* __restrict__ bb2,
                        float* __restrict__ out_opt, float* __restrict__ out_bot, int n){
  __shared__ float Wc[4096];     // concat weights [f=64][c=64]
  __shared__ float hs[16*64];    // 16 node rows
  __shared__ float bc[64];
  __shared__ float Wb2l[32];
  __shared__ float bb2s;
  int tid = threadIdx.x;
  for (int i = tid; i < 4096; i += 256){
    int f = i >> 6, c = i & 63;
    float w = 0.f;
    if (c < 10)       w = Wopt[f*10 + c];
    else if (c >= 32) w = Wb1[f*32 + (c-32)];
    Wc[i] = w;
  }
  if (tid < 64){
    float b = 0.f;
    if (tid < 10)       b = bopt[tid];
    else if (tid >= 32) b = bb1[tid-32];
    bc[tid] = b;
  }
  if (tid >= 64 && tid < 96) Wb2l[tid-64] = Wb2[tid-64];
  if (tid == 96) bb2s = bb2[0];
  size_t base = (size_t)blockIdx.x * 16 * 64;
  size_t lim  = (size_t)n * 64;
  for (int i = tid; i < 1024; i += 256){
    size_t g = base + i;
    hs[i] = (g < lim) ? h[g] : 0.f;
  }
  __syncthreads();
  int w = tid >> 6, c = tid & 63;
  int v0 = blockIdx.x*16 + w*4;
  float acc[4];
  acc[0] = acc[1] = acc[2] = acc[3] = bc[c];
  const float4* r0 = (const float4*)&hs[(w*4+0)*64];
  const float4* r1 = (const float4*)&hs[(w*4+1)*64];
  const float4* r2 = (const float4*)&hs[(w*4+2)*64];
  const float4* r3 = (const float4*)&hs[(w*4+3)*64];
  #pragma unroll
  for (int f4 = 0; f4 < 16; f4++){
    float4 h0 = r0[f4], h1 = r1[f4], h2 = r2[f4], h3 = r3[f4];  // uniform b128
    #pragma unroll
    for (int j = 0; j < 4; j++){
      float wc = Wc[(f4*4+j)*64 + c];   // 2-way bank alias (free)
      acc[0] = fmaf((&h0.x)[j], wc, acc[0]);
      acc[1] = fmaf((&h1.x)[j], wc, acc[1]);
      acc[2] = fmaf((&h2.x)[j], wc, acc[2]);
      acc[3] = fmaf((&h3.x)[j], wc, acc[3]);
    }
  }
  #pragma unroll
  for (int j = 0; j < 4; j++){
    int v = v0 + j;
    if (v < n){                               // wave-uniform
      float a = acc[j];
      if (c < 10) out_opt[(size_t)v*10 + c] = a;
      float contrib = (c >= 32) ? fmaxf(a, 0.f) * Wb2l[c-32] : 0.f;
      contrib += __shfl_xor(contrib, 16);     // reduce within upper half-wave
      contrib += __shfl_xor(contrib, 8);
      contrib += __shfl_xor(contrib, 4);
      contrib += __shfl_xor(contrib, 2);
      contrib += __shfl_xor(contrib, 1);
      if (c == 32) out_bot[v] = 1.f / (1.f + __expf(-(contrib + bb2s)));
    }
  }
}

// per-block partial feature sums of h (grid 256, BW-bound)
__global__ void k_mean(const float* __restrict__ h, float* __restrict__ partial, int n){
  __shared__ float red[256];
  int tid = threadIdx.x;
  int w = tid >> 6, lane = tid & 63;
  float s = 0.f;
  for (int r = blockIdx.x*4 + w; r < n; r += 1024)
    s += h[(size_t)r*64 + lane];
  red[tid] = s;
  __syncthreads();
  if (tid < 64)
    partial[(size_t)blockIdx.x*64 + tid] = red[tid] + red[64+tid] + red[128+tid] + red[192+tid];
}

__global__ void k_embed(const float* __restrict__ partial, float* __restrict__ out_emb,
                        int nb, float invn){
  __shared__ float red[256];
  int tid = threadIdx.x;
  int lane = tid & 63, q = tid >> 6;
  float s = 0.f;
  for (int b = q; b < nb; b += 4) s += partial[(size_t)b*64 + lane];
  red[tid] = s;
  __syncthreads();
  if (tid < 64)
    out_emb[tid] = (red[tid] + red[64+tid] + red[128+tid] + red[192+tid]) * invn;
}

extern "C" void kernel_launch(void* const* d_in, const int* in_sizes, int n_in,
                              void* d_out, int out_size, void* d_ws, size_t ws_size,
                              hipStream_t stream) {
  const float* x    = (const float*)d_in[0];
  const int*   ei   = (const int*)d_in[1];
  const float* W1   = (const float*)d_in[2];
  const float* b1   = (const float*)d_in[3];
  const float* W2   = (const float*)d_in[4];
  const float* a_s  = (const float*)d_in[5];
  const float* a_d  = (const float*)d_in[6];
  const float* b2   = (const float*)d_in[7];
  const float* W3   = (const float*)d_in[8];
  const float* b3   = (const float*)d_in[9];
  const float* Wopt = (const float*)d_in[10];
  const float* bopt = (const float*)d_in[11];
  const float* Wb1  = (const float*)d_in[12];
  const float* bb1  = (const float*)d_in[13];
  const float* Wb2  = (const float*)d_in[14];
  const float* bb2  = (const float*)d_in[15];

  int n = in_sizes[0] / 32;      // 100000
  int e = in_sizes[1] / 2;       // 1250000
  const int* src = ei;
  const int* dst = ei + e;

  // workspace bump allocator (256B aligned); total ~78.6 MB
  char* ws = (char*)d_ws;
  size_t off = 0;
  auto alloc = [&](size_t bytes) -> void* {
    void* p = ws + off;
    off += (bytes + 255) & ~(size_t)255;
    return p;
  };
  int*   cnt     = (int*)  alloc((size_t)n * 4);
  int*   adj     = (int*)  alloc((size_t)n * CAP * 4);
  float* dinv    = (float*)alloc((size_t)n * 4);
  float* als     = (float*)alloc((size_t)n * 4);
  float* ald     = (float*)alloc((size_t)n * 4);
  float* tbuf    = (float*)alloc((size_t)n * 64 * 4);
  float* hbuf    = (float*)alloc((size_t)n * 64 * 4);
  float* partial = (float*)alloc((size_t)256 * 64 * 4);

  float* out_opt = (float*)d_out;
  float* out_bot = out_opt + (size_t)n * 10;
  float* out_emb = out_bot + n;

  int nbN  = (n + 255) / 256;
  int nbE  = (e + 255) / 256;
  int nb4  = (n + 3) / 4;
  int nb16 = (n + 15) / 16;

  k_init<<<nbN, 256, 0, stream>>>(cnt, adj, n);
  k_hist<<<nbE, 256, 0, stream>>>(src, dst, cnt, adj, e);
  k_dinv<<<nbN, 256, 0, stream>>>(cnt, dinv, n);

  // layer 1: GCN(32->64)
  k_gemm<32><<<nb4, 256, 0, stream>>>(x, W1, tbuf, n);
  k_gcn_agg<<<nb4, 256, 0, stream>>>(tbuf, adj, cnt, dinv, b1, hbuf, n);

  // layer 2: GAT(64->64)
  k_gemm_alpha<<<nb4, 256, 0, stream>>>(hbuf, W2, a_s, a_d, tbuf, als, ald, n);
  k_gat_agg<<<nb4, 256, 0, stream>>>(tbuf, adj, cnt, als, ald, b2, hbuf, n);

  // layer 3: GCN(64->64)
  k_gemm<64><<<nb4, 256, 0, stream>>>(hbuf, W3, tbuf, n);
  k_gcn_agg<<<nb4, 256, 0, stream>>>(tbuf, adj, cnt, dinv, b3, hbuf, n);

  // heads + mean embedding
  k_heads<<<nb16, 256, 0, stream>>>(hbuf, Wopt, bopt, Wb1, bb1, Wb2, bb2,
                                    out_opt, out_bot, n);
  k_mean<<<256, 256, 0, stream>>>(hbuf, partial, n);
  k_embed<<<1, 256, 0, stream>>>(partial, out_emb, 256, 1.0f / (float)n);
}

// Round 5
// 615.299 us; speedup vs baseline: 2.0777x; 1.5762x over previous
//
#include <hip/hip_runtime.h>
#include <hip/hip_bf16.h>

// WorkflowGNN: GCN(32->64)+ReLU, GAT(64->64,h=1)+ReLU, GCN(64->64)+ReLU,
// heads: opt [N,10], bottleneck [N,1], mean-embed [64]. f32 in/out.
// R4->R5: kill LDS in steady state (LDS is CU-wide: 16 b128/node serialized
// across 4 SIMDs => ~45us floor). Weights live in VGPRs (lane=out-col),
// node rows are wave-uniform scalar loads (readfirstlane), persistent grids
// amortize weight loads. Aggs: dinv pre-scaled into t, row idx via __shfl.

#define CAP 64

__device__ __forceinline__ int uwave(){                 // wave id, known-uniform
  return __builtin_amdgcn_readfirstlane(threadIdx.x >> 6);
}

// cnt[v]=1 (self-loop), adj[v][0]=v
__global__ void k_init(int* __restrict__ cnt, int* __restrict__ adj, int n){
  int v = blockIdx.x*blockDim.x + threadIdx.x;
  if (v < n){ cnt[v] = 1; adj[(size_t)v*CAP] = v; }
}

__global__ void k_hist(const int* __restrict__ src, const int* __restrict__ dst,
                       int* __restrict__ cnt, int* __restrict__ adj, int e){
  int i = blockIdx.x*blockDim.x + threadIdx.x;
  if (i < e){
    int d = dst[i];
    int pos = atomicAdd(&cnt[d], 1);
    if (pos < CAP) adj[(size_t)d*CAP + pos] = src[i];
  }
}

__global__ void k_dinv(const int* __restrict__ cnt, float* __restrict__ dinv, int n){
  int v = blockIdx.x*blockDim.x + threadIdx.x;
  if (v < n) dinv[v] = rsqrtf((float)cnt[v]);
}

// t[v][lane] = (x[v] . W[:,lane]) * (SCALE ? dinv[v] : 1)
// weights in VGPRs, x row wave-uniform (scalarizable), persistent grid.
template<int K, bool SCALE>
__global__ __launch_bounds__(256, 4) void k_gemm(const float* __restrict__ x,
                       const float* __restrict__ W, const float* __restrict__ dinv,
                       float* __restrict__ t, int n){
  int lane = threadIdx.x & 63;
  int gw = blockIdx.x*4 + uwave();
  int nw = gridDim.x*4;
  float wreg[K];
  #pragma unroll
  for (int k = 0; k < K; k++) wreg[k] = W[k*64 + lane];   // coalesced, once
  for (int v = gw; v < n; v += nw){                        // uniform loop
    const float4* xr = (const float4*)(x + (size_t)v*K);   // uniform row ptr
    float acc = 0.f;
    #pragma unroll
    for (int k4 = 0; k4 < K/4; k4++){
      float4 xv = xr[k4];                                  // broadcast/scalar
      acc = fmaf(xv.x, wreg[k4*4+0], acc);
      acc = fmaf(xv.y, wreg[k4*4+1], acc);
      acc = fmaf(xv.z, wreg[k4*4+2], acc);
      acc = fmaf(xv.w, wreg[k4*4+3], acc);
    }
    if (SCALE) acc *= dinv[v];                             // uniform
    t[(size_t)v*64 + lane] = acc;                          // coalesced 256B
  }
}

// K=64 GEMM (unscaled) + fused alpha_src/alpha_dst dots
__global__ __launch_bounds__(256, 4) void k_gemm_alpha(const float* __restrict__ x,
                       const float* __restrict__ W,
                       const float* __restrict__ asrc, const float* __restrict__ adst,
                       float* __restrict__ t, float* __restrict__ als,
                       float* __restrict__ ald, int n){
  int lane = threadIdx.x & 63;
  int gw = blockIdx.x*4 + uwave();
  int nw = gridDim.x*4;
  float wreg[64];
  #pragma unroll
  for (int k = 0; k < 64; k++) wreg[k] = W[k*64 + lane];
  float asr = asrc[lane], adr = adst[lane];
  for (int v = gw; v < n; v += nw){
    const float4* xr = (const float4*)(x + (size_t)v*64);
    float acc = 0.f;
    #pragma unroll
    for (int k4 = 0; k4 < 16; k4++){
      float4 xv = xr[k4];
      acc = fmaf(xv.x, wreg[k4*4+0], acc);
      acc = fmaf(xv.y, wreg[k4*4+1], acc);
      acc = fmaf(xv.z, wreg[k4*4+2], acc);
      acc = fmaf(xv.w, wreg[k4*4+3], acc);
    }
    t[(size_t)v*64 + lane] = acc;
    float s1 = acc * asr, s2 = acc * adr;
    #pragma unroll
    for (int off = 32; off; off >>= 1){
      s1 += __shfl_xor(s1, off);
      s2 += __shfl_xor(s2, off);
    }
    if (lane == 0){ als[v] = s1; ald[v] = s2; }
  }
}

// h[v][f] = relu( dinv[v] * sum_u t'[u][f] + b[f] ), t' pre-scaled by dinv[u]
__global__ void k_gcn_agg(const float* __restrict__ t, const int* __restrict__ adj,
                          const int* __restrict__ cnt, const float* __restrict__ dinv,
                          const float* __restrict__ b, float* __restrict__ h, int n){
  int lane = threadIdx.x & 63;
  int v = blockIdx.x*4 + uwave();
  if (v >= n) return;                       // uniform
  int c = min(cnt[v], CAP);                 // scalar
  const int* row = adj + (size_t)v*CAP;
  int ureg = row[lane];                     // coalesced; lanes>=c unused
  float acc = 0.f;
  #pragma unroll 4
  for (int j = 0; j < c; j++){
    int u = __shfl(ureg, j);
    acc += t[(size_t)u*64 + lane];          // coalesced 256B row
  }
  h[(size_t)v*64 + lane] = fmaxf(fmaf(acc, dinv[v], b[lane]), 0.f);
}

// GAT: per-dst softmax over in-edges (computed once, kept in regs/shuffles)
__global__ void k_gat_agg(const float* __restrict__ g, const int* __restrict__ adj,
                          const int* __restrict__ cnt, const float* __restrict__ als,
                          const float* __restrict__ ald, const float* __restrict__ b,
                          float* __restrict__ h, int n){
  int lane = threadIdx.x & 63;
  int v = blockIdx.x*4 + uwave();
  if (v >= n) return;
  int c = min(cnt[v], CAP);
  const int* row = adj + (size_t)v*CAP;
  int ureg = (lane < c) ? row[lane] : v;    // safe index for gather
  float adv = ald[v];                       // uniform
  float e = als[ureg] + adv;                // 4B gather (lane=edge)
  e = e > 0.f ? e : 0.2f*e;
  float em = (lane < c) ? e : -1e30f;
  #pragma unroll
  for (int off = 32; off; off >>= 1) em = fmaxf(em, __shfl_xor(em, off));
  float p = (lane < c) ? __expf(e - em) : 0.f;
  float s = p;
  #pragma unroll
  for (int off = 32; off; off >>= 1) s += __shfl_xor(s, off);
  float inv = 1.f / s;
  float acc = 0.f;
  #pragma unroll 4
  for (int j = 0; j < c; j++){
    float w = __shfl(p, j);
    int   u = __shfl(ureg, j);
    acc = fmaf(w, g[(size_t)u*64 + lane], acc);
  }
  h[(size_t)v*64 + lane] = fmaxf(fmaf(acc, inv, b[lane]), 0.f);
}

// heads: lane = concat col (0..9 opt | 32..63 bottleneck hidden), weights in
// VGPRs, node rows wave-uniform, persistent grid.
__global__ __launch_bounds__(256, 4) void k_heads(const float* __restrict__ h,
                        const float* __restrict__ Wopt, const float* __restrict__ bopt,
                        const float* __restrict__ Wb1, const float* __restrict__ bb1,
                        const float* __restrict__ Wb2, const float* __restrict__ bb2,
                        float* __restrict__ out_opt, float* __restrict__ out_bot, int n){
  __shared__ float Wc[4096];
  __shared__ float bc[64];
  int tid = threadIdx.x;
  for (int i = tid; i < 4096; i += 256){
    int f = i >> 6, c = i & 63;
    float w = 0.f;
    if (c < 10)       w = Wopt[f*10 + c];
    else if (c >= 32) w = Wb1[f*32 + (c-32)];
    Wc[i] = w;
  }
  if (tid < 64){
    float bv = 0.f;
    if (tid < 10)       bv = bopt[tid];
    else if (tid >= 32) bv = bb1[tid-32];
    bc[tid] = bv;
  }
  __syncthreads();
  int lane = tid & 63;
  float wreg[64];
  #pragma unroll
  for (int f = 0; f < 64; f++) wreg[f] = Wc[f*64 + lane];  // once per wave
  float bcr  = bc[lane];
  float wb2r = (lane >= 32) ? Wb2[lane-32] : 0.f;
  float bb2r = bb2[0];
  int gw = blockIdx.x*4 + uwave();
  int nw = gridDim.x*4;
  for (int v = gw; v < n; v += nw){
    const float4* hr = (const float4*)(h + (size_t)v*64);
    float acc = bcr;
    #pragma unroll
    for (int f4 = 0; f4 < 16; f4++){
      float4 hv = hr[f4];
      acc = fmaf(hv.x, wreg[f4*4+0], acc);
      acc = fmaf(hv.y, wreg[f4*4+1], acc);
      acc = fmaf(hv.z, wreg[f4*4+2], acc);
      acc = fmaf(hv.w, wreg[f4*4+3], acc);
    }
    if (lane < 10) out_opt[(size_t)v*10 + lane] = acc;
    float contrib = (lane >= 32) ? fmaxf(acc, 0.f) * wb2r : 0.f;
    #pragma unroll
    for (int off = 32; off; off >>= 1) contrib += __shfl_xor(contrib, off);
    if (lane == 0) out_bot[v] = 1.f / (1.f + __expf(-(contrib + bb2r)));
  }
}

// per-block partial feature sums of h
__global__ void k_mean(const float* __restrict__ h, float* __restrict__ partial, int n){
  __shared__ float red[256];
  int tid = threadIdx.x;
  int w = tid >> 6, lane = tid & 63;
  float s = 0.f;
  for (int r = blockIdx.x*4 + w; r < n; r += 1024)
    s += h[(size_t)r*64 + lane];
  red[tid] = s;
  __syncthreads();
  if (tid < 64)
    partial[(size_t)blockIdx.x*64 + tid] = red[tid] + red[64+tid] + red[128+tid] + red[192+tid];
}

__global__ void k_embed(const float* __restrict__ partial, float* __restrict__ out_emb,
                        int nb, float invn){
  __shared__ float red[256];
  int tid = threadIdx.x;
  int lane = tid & 63, q = tid >> 6;
  float s = 0.f;
  for (int b = q; b < nb; b += 4) s += partial[(size_t)b*64 + lane];
  red[tid] = s;
  __syncthreads();
  if (tid < 64)
    out_emb[tid] = (red[tid] + red[64+tid] + red[128+tid] + red[192+tid]) * invn;
}

extern "C" void kernel_launch(void* const* d_in, const int* in_sizes, int n_in,
                              void* d_out, int out_size, void* d_ws, size_t ws_size,
                              hipStream_t stream) {
  const float* x    = (const float*)d_in[0];
  const int*   ei   = (const int*)d_in[1];
  const float* W1   = (const float*)d_in[2];
  const float* b1   = (const float*)d_in[3];
  const float* W2   = (const float*)d_in[4];
  const float* a_s  = (const float*)d_in[5];
  const float* a_d  = (const float*)d_in[6];
  const float* b2   = (const float*)d_in[7];
  const float* W3   = (const float*)d_in[8];
  const float* b3   = (const float*)d_in[9];
  const float* Wopt = (const float*)d_in[10];
  const float* bopt = (const float*)d_in[11];
  const float* Wb1  = (const float*)d_in[12];
  const float* bb1  = (const float*)d_in[13];
  const float* Wb2  = (const float*)d_in[14];
  const float* bb2  = (const float*)d_in[15];

  int n = in_sizes[0] / 32;      // 100000
  int e = in_sizes[1] / 2;       // 1250000
  const int* src = ei;
  const int* dst = ei + e;

  char* ws = (char*)d_ws;
  size_t off = 0;
  auto alloc = [&](size_t bytes) -> void* {
    void* p = ws + off;
    off += (bytes + 255) & ~(size_t)255;
    return p;
  };
  int*   cnt     = (int*)  alloc((size_t)n * 4);
  int*   adj     = (int*)  alloc((size_t)n * CAP * 4);
  float* dinv    = (float*)alloc((size_t)n * 4);
  float* als     = (float*)alloc((size_t)n * 4);
  float* ald     = (float*)alloc((size_t)n * 4);
  float* tbuf    = (float*)alloc((size_t)n * 64 * 4);
  float* hbuf    = (float*)alloc((size_t)n * 64 * 4);
  float* partial = (float*)alloc((size_t)256 * 64 * 4);

  float* out_opt = (float*)d_out;
  float* out_bot = out_opt + (size_t)n * 10;
  float* out_emb = out_bot + n;

  int nbN  = (n + 255) / 256;
  int nbE  = (e + 255) / 256;
  int nb4  = (n + 3) / 4;

  k_init<<<nbN, 256, 0, stream>>>(cnt, adj, n);
  k_hist<<<nbE, 256, 0, stream>>>(src, dst, cnt, adj, e);
  k_dinv<<<nbN, 256, 0, stream>>>(cnt, dinv, n);

  // layer 1: GCN(32->64), t pre-scaled by dinv[v]
  k_gemm<32, true><<<1024, 256, 0, stream>>>(x, W1, dinv, tbuf, n);
  k_gcn_agg<<<nb4, 256, 0, stream>>>(tbuf, adj, cnt, dinv, b1, hbuf, n);

  // layer 2: GAT(64->64), unscaled
  k_gemm_alpha<<<1024, 256, 0, stream>>>(hbuf, W2, a_s, a_d, tbuf, als, ald, n);
  k_gat_agg<<<nb4, 256, 0, stream>>>(tbuf, adj, cnt, als, ald, b2, hbuf, n);

  // layer 3: GCN(64->64), pre-scaled
  k_gemm<64, true><<<1024, 256, 0, stream>>>(hbuf, W3, dinv, tbuf, n);
  k_gcn_agg<<<nb4, 256, 0, stream>>>(tbuf, adj, cnt, dinv, b3, hbuf, n);

  // heads + mean embedding
  k_heads<<<1024, 256, 0, stream>>>(hbuf, Wopt, bopt, Wb1, bb1, Wb2, bb2,
                                    out_opt, out_bot, n);
  k_mean<<<256, 256, 0, stream>>>(hbuf, partial, n);
  k_embed<<<1, 256, 0, stream>>>(partial, out_emb, 256, 1.0f / (float)n);
}

// Round 6
// 545.964 us; speedup vs baseline: 2.3416x; 1.1270x over previous
//
#include <hip/hip_runtime.h>
#include <hip/hip_bf16.h>

// WorkflowGNN: GCN(32->64)+ReLU, GAT(64->64,h=1)+ReLU, GCN(64->64)+ReLU,
// heads: opt [N,10], bottleneck [N,1], mean-embed [64]. f32 in/out.
// R5->R6: aggs were issue/latency-bound (VALU 25%, HBM 24%): 14 vmem + 27
// bpermute per node. Now 4 lane-groups x 16 lanes gather 4 neighbor rows per
// dwordx4 instruction (vmem/node 14->4.5, bpermute/node 27->~15); adjacency
// padded with zero-row index n so group loops are branch-free.

#define CAP 64

__device__ __forceinline__ int uwave(){                 // wave id, known-uniform
  return __builtin_amdgcn_readfirstlane(threadIdx.x >> 6);
}

// one wave per node: cnt[v]=1, adj[v][0]=v, adj[v][1..63]=n (pad -> zero row)
__global__ void k_init(int* __restrict__ cnt, int* __restrict__ adj, int n){
  int lane = threadIdx.x & 63;
  int v = blockIdx.x*4 + uwave();
  if (v >= n) return;
  adj[(size_t)v*CAP + lane] = (lane == 0) ? v : n;
  if (lane == 0) cnt[v] = 1;
}

// zero pad row of t (index n)
__global__ void k_zero(float* __restrict__ t, int n){
  if (threadIdx.x < 64) t[(size_t)n*64 + threadIdx.x] = 0.f;
}

__global__ void k_hist(const int* __restrict__ src, const int* __restrict__ dst,
                       int* __restrict__ cnt, int* __restrict__ adj, int e){
  int i = blockIdx.x*blockDim.x + threadIdx.x;
  if (i < e){
    int d = dst[i];
    int pos = atomicAdd(&cnt[d], 1);
    if (pos < CAP) adj[(size_t)d*CAP + pos] = src[i];
  }
}

__global__ void k_dinv(const int* __restrict__ cnt, float* __restrict__ dinv, int n){
  int v = blockIdx.x*blockDim.x + threadIdx.x;
  if (v < n) dinv[v] = rsqrtf((float)cnt[v]);
}

// t[v][lane] = (x[v] . W[:,lane]) * (SCALE ? dinv[v] : 1)
template<int K, bool SCALE>
__global__ __launch_bounds__(256, 4) void k_gemm(const float* __restrict__ x,
                       const float* __restrict__ W, const float* __restrict__ dinv,
                       float* __restrict__ t, int n){
  int lane = threadIdx.x & 63;
  int gw = blockIdx.x*4 + uwave();
  int nw = gridDim.x*4;
  float wreg[K];
  #pragma unroll
  for (int k = 0; k < K; k++) wreg[k] = W[k*64 + lane];   // coalesced, once
  for (int v = gw; v < n; v += nw){                        // uniform loop
    const float4* xr = (const float4*)(x + (size_t)v*K);   // uniform row ptr
    float acc = 0.f;
    #pragma unroll
    for (int k4 = 0; k4 < K/4; k4++){
      float4 xv = xr[k4];                                  // scalarized
      acc = fmaf(xv.x, wreg[k4*4+0], acc);
      acc = fmaf(xv.y, wreg[k4*4+1], acc);
      acc = fmaf(xv.z, wreg[k4*4+2], acc);
      acc = fmaf(xv.w, wreg[k4*4+3], acc);
    }
    if (SCALE) acc *= dinv[v];                             // uniform
    t[(size_t)v*64 + lane] = acc;                          // coalesced 256B
  }
}

// K=64 GEMM (unscaled) + fused alpha_src/alpha_dst dots
__global__ __launch_bounds__(256, 4) void k_gemm_alpha(const float* __restrict__ x,
                       const float* __restrict__ W,
                       const float* __restrict__ asrc, const float* __restrict__ adst,
                       float* __restrict__ t, float* __restrict__ als,
                       float* __restrict__ ald, int n){
  int lane = threadIdx.x & 63;
  int gw = blockIdx.x*4 + uwave();
  int nw = gridDim.x*4;
  float wreg[64];
  #pragma unroll
  for (int k = 0; k < 64; k++) wreg[k] = W[k*64 + lane];
  float asr = asrc[lane], adr = adst[lane];
  for (int v = gw; v < n; v += nw){
    const float4* xr = (const float4*)(x + (size_t)v*64);
    float acc = 0.f;
    #pragma unroll
    for (int k4 = 0; k4 < 16; k4++){
      float4 xv = xr[k4];
      acc = fmaf(xv.x, wreg[k4*4+0], acc);
      acc = fmaf(xv.y, wreg[k4*4+1], acc);
      acc = fmaf(xv.z, wreg[k4*4+2], acc);
      acc = fmaf(xv.w, wreg[k4*4+3], acc);
    }
    t[(size_t)v*64 + lane] = acc;
    float s1 = acc * asr, s2 = acc * adr;
    #pragma unroll
    for (int off = 32; off; off >>= 1){
      s1 += __shfl_xor(s1, off);
      s2 += __shfl_xor(s2, off);
    }
    if (lane == 0){ als[v] = s1; ald[v] = s2; }
  }
}

// GCN agg: 4 groups x 16 lanes, one dwordx4 per lane = 4 rows per iteration.
// t pre-scaled by dinv[u]; pads point at zero row n.
__global__ __launch_bounds__(256) void k_gcn_agg(const float* __restrict__ t,
                          const int* __restrict__ adj, const int* __restrict__ cnt,
                          const float* __restrict__ dinv, const float* __restrict__ b,
                          float* __restrict__ h, int n){
  int lane = threadIdx.x & 63;
  int v = blockIdx.x*4 + uwave();
  if (v >= n) return;                         // uniform
  int c = min(cnt[v], CAP);                   // scalar
  const int* row = adj + (size_t)v*CAP;
  int ureg = row[lane];                       // coalesced; pads = n
  int g = lane >> 4, q = lane & 15;
  float4 acc = {0.f, 0.f, 0.f, 0.f};
  int iters = (c + 3) >> 2;
  #pragma unroll 2
  for (int jj = 0; jj < iters; jj++){
    int u = __shfl(ureg, jj*4 + g);           // my group's row
    float4 tv = ((const float4*)(t + (size_t)u*64))[q];   // 16x16B = 256B/row
    acc.x += tv.x; acc.y += tv.y; acc.z += tv.z; acc.w += tv.w;
  }
  // combine the 4 groups (lanes l, l^16, l^32 hold same features)
  acc.x += __shfl_xor(acc.x, 16); acc.y += __shfl_xor(acc.y, 16);
  acc.z += __shfl_xor(acc.z, 16); acc.w += __shfl_xor(acc.w, 16);
  acc.x += __shfl_xor(acc.x, 32); acc.y += __shfl_xor(acc.y, 32);
  acc.z += __shfl_xor(acc.z, 32); acc.w += __shfl_xor(acc.w, 32);
  float dv = dinv[v];
  float4 bb = ((const float4*)b)[q];
  float4 res;
  res.x = fmaxf(fmaf(acc.x, dv, bb.x), 0.f);
  res.y = fmaxf(fmaf(acc.y, dv, bb.y), 0.f);
  res.z = fmaxf(fmaf(acc.z, dv, bb.z), 0.f);
  res.w = fmaxf(fmaf(acc.w, dv, bb.w), 0.f);
  if (lane < 16) ((float4*)(h + (size_t)v*64))[q] = res;  // 256B store
}

// GAT agg: softmax weights per edge, then grouped float4 gather like GCN.
__global__ __launch_bounds__(256) void k_gat_agg(const float* __restrict__ t,
                          const int* __restrict__ adj, const int* __restrict__ cnt,
                          const float* __restrict__ als, const float* __restrict__ ald,
                          const float* __restrict__ b, float* __restrict__ h, int n){
  int lane = threadIdx.x & 63;
  int v = blockIdx.x*4 + uwave();
  if (v >= n) return;
  int c = min(cnt[v], CAP);
  const int* row = adj + (size_t)v*CAP;
  int ureg = row[lane];                       // pads = n
  float adv = ald[v];                         // uniform
  float e = als[ureg] + adv;                  // 4B gather (lane=edge; pad reads als[n], masked)
  e = e > 0.f ? e : 0.2f*e;
  float em = (lane < c) ? e : -1e30f;
  #pragma unroll
  for (int off = 32; off; off >>= 1) em = fmaxf(em, __shfl_xor(em, off));
  float p = (lane < c) ? __expf(e - em) : 0.f;
  float s = p;
  #pragma unroll
  for (int off = 32; off; off >>= 1) s += __shfl_xor(s, off);
  float inv = 1.f / s;
  int g = lane >> 4, q = lane & 15;
  float4 acc = {0.f, 0.f, 0.f, 0.f};
  int iters = (c + 3) >> 2;
  #pragma unroll 2
  for (int jj = 0; jj < iters; jj++){
    int   u = __shfl(ureg, jj*4 + g);
    float w = __shfl(p,    jj*4 + g);         // pad slots have p=0
    float4 tv = ((const float4*)(t + (size_t)u*64))[q];
    acc.x = fmaf(w, tv.x, acc.x); acc.y = fmaf(w, tv.y, acc.y);
    acc.z = fmaf(w, tv.z, acc.z); acc.w = fmaf(w, tv.w, acc.w);
  }
  acc.x += __shfl_xor(acc.x, 16); acc.y += __shfl_xor(acc.y, 16);
  acc.z += __shfl_xor(acc.z, 16); acc.w += __shfl_xor(acc.w, 16);
  acc.x += __shfl_xor(acc.x, 32); acc.y += __shfl_xor(acc.y, 32);
  acc.z += __shfl_xor(acc.z, 32); acc.w += __shfl_xor(acc.w, 32);
  float4 bb = ((const float4*)b)[q];
  float4 res;
  res.x = fmaxf(fmaf(acc.x, inv, bb.x), 0.f);
  res.y = fmaxf(fmaf(acc.y, inv, bb.y), 0.f);
  res.z = fmaxf(fmaf(acc.z, inv, bb.z), 0.f);
  res.w = fmaxf(fmaf(acc.w, inv, bb.w), 0.f);
  if (lane < 16) ((float4*)(h + (size_t)v*64))[q] = res;
}

// heads: lane = concat col (0..9 opt | 32..63 bottleneck hidden), weights in
// VGPRs, node rows wave-uniform, persistent grid.
__global__ __launch_bounds__(256, 4) void k_heads(const float* __restrict__ h,
                        const float* __restrict__ Wopt, const float* __restrict__ bopt,
                        const float* __restrict__ Wb1, const float* __restrict__ bb1,
                        const float* __restrict__ Wb2, const float* __restrict__ bb2,
                        float* __restrict__ out_opt, float* __restrict__ out_bot, int n){
  __shared__ float Wc[4096];
  __shared__ float bc[64];
  int tid = threadIdx.x;
  for (int i = tid; i < 4096; i += 256){
    int f = i >> 6, c = i & 63;
    float w = 0.f;
    if (c < 10)       w = Wopt[f*10 + c];
    else if (c >= 32) w = Wb1[f*32 + (c-32)];
    Wc[i] = w;
  }
  if (tid < 64){
    float bv = 0.f;
    if (tid < 10)       bv = bopt[tid];
    else if (tid >= 32) bv = bb1[tid-32];
    bc[tid] = bv;
  }
  __syncthreads();
  int lane = tid & 63;
  float wreg[64];
  #pragma unroll
  for (int f = 0; f < 64; f++) wreg[f] = Wc[f*64 + lane];  // once per wave
  float bcr  = bc[lane];
  float wb2r = (lane >= 32) ? Wb2[lane-32] : 0.f;
  float bb2r = bb2[0];
  int gw = blockIdx.x*4 + uwave();
  int nw = gridDim.x*4;
  for (int v = gw; v < n; v += nw){
    const float4* hr = (const float4*)(h + (size_t)v*64);
    float acc = bcr;
    #pragma unroll
    for (int f4 = 0; f4 < 16; f4++){
      float4 hv = hr[f4];
      acc = fmaf(hv.x, wreg[f4*4+0], acc);
      acc = fmaf(hv.y, wreg[f4*4+1], acc);
      acc = fmaf(hv.z, wreg[f4*4+2], acc);
      acc = fmaf(hv.w, wreg[f4*4+3], acc);
    }
    if (lane < 10) out_opt[(size_t)v*10 + lane] = acc;
    float contrib = (lane >= 32) ? fmaxf(acc, 0.f) * wb2r : 0.f;
    #pragma unroll
    for (int off = 32; off; off >>= 1) contrib += __shfl_xor(contrib, off);
    if (lane == 0) out_bot[v] = 1.f / (1.f + __expf(-(contrib + bb2r)));
  }
}

// per-block partial feature sums of h
__global__ void k_mean(const float* __restrict__ h, float* __restrict__ partial, int n){
  __shared__ float red[256];
  int tid = threadIdx.x;
  int w = tid >> 6, lane = tid & 63;
  float s = 0.f;
  for (int r = blockIdx.x*4 + w; r < n; r += 1024)
    s += h[(size_t)r*64 + lane];
  red[tid] = s;
  __syncthreads();
  if (tid < 64)
    partial[(size_t)blockIdx.x*64 + tid] = red[tid] + red[64+tid] + red[128+tid] + red[192+tid];
}

__global__ void k_embed(const float* __restrict__ partial, float* __restrict__ out_emb,
                        int nb, float invn){
  __shared__ float red[256];
  int tid = threadIdx.x;
  int lane = tid & 63, q = tid >> 6;
  float s = 0.f;
  for (int b = q; b < nb; b += 4) s += partial[(size_t)b*64 + lane];
  red[tid] = s;
  __syncthreads();
  if (tid < 64)
    out_emb[tid] = (red[tid] + red[64+tid] + red[128+tid] + red[192+tid]) * invn;
}

extern "C" void kernel_launch(void* const* d_in, const int* in_sizes, int n_in,
                              void* d_out, int out_size, void* d_ws, size_t ws_size,
                              hipStream_t stream) {
  const float* x    = (const float*)d_in[0];
  const int*   ei   = (const int*)d_in[1];
  const float* W1   = (const float*)d_in[2];
  const float* b1   = (const float*)d_in[3];
  const float* W2   = (const float*)d_in[4];
  const float* a_s  = (const float*)d_in[5];
  const float* a_d  = (const float*)d_in[6];
  const float* b2   = (const float*)d_in[7];
  const float* W3   = (const float*)d_in[8];
  const float* b3   = (const float*)d_in[9];
  const float* Wopt = (const float*)d_in[10];
  const float* bopt = (const float*)d_in[11];
  const float* Wb1  = (const float*)d_in[12];
  const float* bb1  = (const float*)d_in[13];
  const float* Wb2  = (const float*)d_in[14];
  const float* bb2  = (const float*)d_in[15];

  int n = in_sizes[0] / 32;      // 100000
  int e = in_sizes[1] / 2;       // 1250000
  const int* src = ei;
  const int* dst = ei + e;

  char* ws = (char*)d_ws;
  size_t off = 0;
  auto alloc = [&](size_t bytes) -> void* {
    void* p = ws + off;
    off += (bytes + 255) & ~(size_t)255;
    return p;
  };
  int*   cnt     = (int*)  alloc((size_t)n * 4);
  int*   adj     = (int*)  alloc((size_t)n * CAP * 4);
  float* dinv    = (float*)alloc((size_t)n * 4);
  float* als     = (float*)alloc((size_t)(n+64) * 4);   // +pad (read via adj pad idx)
  float* ald     = (float*)alloc((size_t)n * 4);
  float* tbuf    = (float*)alloc((size_t)(n+1) * 64 * 4); // +zero row n
  float* hbuf    = (float*)alloc((size_t)n * 64 * 4);
  float* partial = (float*)alloc((size_t)256 * 64 * 4);

  float* out_opt = (float*)d_out;
  float* out_bot = out_opt + (size_t)n * 10;
  float* out_emb = out_bot + n;

  int nbN  = (n + 255) / 256;
  int nbE  = (e + 255) / 256;
  int nb4  = (n + 3) / 4;

  k_init<<<nb4, 256, 0, stream>>>(cnt, adj, n);
  k_zero<<<1, 64, 0, stream>>>(tbuf, n);
  k_hist<<<nbE, 256, 0, stream>>>(src, dst, cnt, adj, e);
  k_dinv<<<nbN, 256, 0, stream>>>(cnt, dinv, n);

  // layer 1: GCN(32->64), t pre-scaled by dinv[v]
  k_gemm<32, true><<<1024, 256, 0, stream>>>(x, W1, dinv, tbuf, n);
  k_gcn_agg<<<nb4, 256, 0, stream>>>(tbuf, adj, cnt, dinv, b1, hbuf, n);

  // layer 2: GAT(64->64), unscaled
  k_gemm_alpha<<<1024, 256, 0, stream>>>(hbuf, W2, a_s, a_d, tbuf, als, ald, n);
  k_gat_agg<<<nb4, 256, 0, stream>>>(tbuf, adj, cnt, als, ald, b2, hbuf, n);

  // layer 3: GCN(64->64), pre-scaled
  k_gemm<64, true><<<1024, 256, 0, stream>>>(hbuf, W3, dinv, tbuf, n);
  k_gcn_agg<<<nb4, 256, 0, stream>>>(tbuf, adj, cnt, dinv, b3, hbuf, n);

  // heads + mean embedding
  k_heads<<<1024, 256, 0, stream>>>(hbuf, Wopt, bopt, Wb1, bb1, Wb2, bb2,
                                    out_opt, out_bot, n);
  k_mean<<<256, 256, 0, stream>>>(hbuf, partial, n);
  k_embed<<<1, 256, 0, stream>>>(partial, out_emb, 256, 1.0f / (float)n);
}

// Round 7
// 511.841 us; speedup vs baseline: 2.4977x; 1.0667x over previous
//
#include <hip/hip_runtime.h>
#include <hip/hip_bf16.h>

// WorkflowGNN: GCN(32->64)+ReLU, GAT(64->64,h=1)+ReLU, GCN(64->64)+ReLU,
// heads: opt [N,10], bottleneck [N,1], mean-embed [64]. f32 in/out.
// R6->R7: k_hist was random-write bound (WRITE_SIZE 75MB for 5MB payload:
// every 4B scatter = 64B HBM line, x8 XCD dirty replication). Now XCD-sliced:
// slice = blockIdx&7 owns dst range [slice*n/8,..): per-XCD write window
// ~850KB -> L2-resident, one writeback/line. Also: k_zero folded into k_init,
// k_dinv eliminated (inline rsqrt(cnt)), k_mean fused into k_heads.

#define CAP 64

__device__ __forceinline__ int uwave(){                 // wave id, known-uniform
  return __builtin_amdgcn_readfirstlane(threadIdx.x >> 6);
}

// one wave per node: cnt[v]=1, adj[v][0]=v, adj[v][1..63]=n (pad -> zero row);
// block 0 zeroes t row n.
__global__ void k_init(int* __restrict__ cnt, int* __restrict__ adj,
                       float* __restrict__ t, int n){
  int lane = threadIdx.x & 63;
  if (blockIdx.x == 0 && threadIdx.x < 64) t[(size_t)n*64 + threadIdx.x] = 0.f;
  int v = blockIdx.x*4 + uwave();
  if (v >= n) return;
  adj[(size_t)v*CAP + lane] = (lane == 0) ? v : n;
  if (lane == 0) cnt[v] = 1;
}

// XCD-sliced histogram: slice = blockIdx&7 processes only dst in its range,
// so each XCD's atomics/scatter-writes stay in its own L2.
__global__ void k_hist(const int* __restrict__ src, const int* __restrict__ dst,
                       int* __restrict__ cnt, int* __restrict__ adj,
                       int e, int nper){
  int slice = blockIdx.x & 7;
  int i = (blockIdx.x >> 3)*blockDim.x + threadIdx.x;
  if (i >= e) return;
  int d = dst[i];
  int lo = slice*nper;
  if (d < lo || d >= lo + nper) return;
  int pos = atomicAdd(&cnt[d], 1);
  if (pos < CAP) adj[(size_t)d*CAP + pos] = src[i];
}

// t[v][lane] = (x[v] . W[:,lane]) * (SCALE ? rsqrt(cnt[v]) : 1)
template<int K, bool SCALE>
__global__ __launch_bounds__(256, 4) void k_gemm(const float* __restrict__ x,
                       const float* __restrict__ W, const int* __restrict__ cnt,
                       float* __restrict__ t, int n){
  int lane = threadIdx.x & 63;
  int gw = blockIdx.x*4 + uwave();
  int nw = gridDim.x*4;
  float wreg[K];
  #pragma unroll
  for (int k = 0; k < K; k++) wreg[k] = W[k*64 + lane];   // coalesced, once
  for (int v = gw; v < n; v += nw){                        // uniform loop
    const float4* xr = (const float4*)(x + (size_t)v*K);   // uniform row ptr
    float acc = 0.f;
    #pragma unroll
    for (int k4 = 0; k4 < K/4; k4++){
      float4 xv = xr[k4];                                  // scalarized
      acc = fmaf(xv.x, wreg[k4*4+0], acc);
      acc = fmaf(xv.y, wreg[k4*4+1], acc);
      acc = fmaf(xv.z, wreg[k4*4+2], acc);
      acc = fmaf(xv.w, wreg[k4*4+3], acc);
    }
    if (SCALE) acc *= rsqrtf((float)cnt[v]);               // uniform
    t[(size_t)v*64 + lane] = acc;                          // coalesced 256B
  }
}

// K=64 GEMM (unscaled) + fused alpha_src/alpha_dst dots
__global__ __launch_bounds__(256, 4) void k_gemm_alpha(const float* __restrict__ x,
                       const float* __restrict__ W,
                       const float* __restrict__ asrc, const float* __restrict__ adst,
                       float* __restrict__ t, float* __restrict__ als,
                       float* __restrict__ ald, int n){
  int lane = threadIdx.x & 63;
  int gw = blockIdx.x*4 + uwave();
  int nw = gridDim.x*4;
  float wreg[64];
  #pragma unroll
  for (int k = 0; k < 64; k++) wreg[k] = W[k*64 + lane];
  float asr = asrc[lane], adr = adst[lane];
  for (int v = gw; v < n; v += nw){
    const float4* xr = (const float4*)(x + (size_t)v*64);
    float acc = 0.f;
    #pragma unroll
    for (int k4 = 0; k4 < 16; k4++){
      float4 xv = xr[k4];
      acc = fmaf(xv.x, wreg[k4*4+0], acc);
      acc = fmaf(xv.y, wreg[k4*4+1], acc);
      acc = fmaf(xv.z, wreg[k4*4+2], acc);
      acc = fmaf(xv.w, wreg[k4*4+3], acc);
    }
    t[(size_t)v*64 + lane] = acc;
    float s1 = acc * asr, s2 = acc * adr;
    #pragma unroll
    for (int off = 32; off; off >>= 1){
      s1 += __shfl_xor(s1, off);
      s2 += __shfl_xor(s2, off);
    }
    if (lane == 0){ als[v] = s1; ald[v] = s2; }
  }
}

// GCN agg: 4 groups x 16 lanes, one dwordx4 per lane = 4 rows per iteration.
// t pre-scaled by rsqrt(cnt[u]); pads point at zero row n.
__global__ __launch_bounds__(256) void k_gcn_agg(const float* __restrict__ t,
                          const int* __restrict__ adj, const int* __restrict__ cnt,
                          const float* __restrict__ b, float* __restrict__ h, int n){
  int lane = threadIdx.x & 63;
  int v = blockIdx.x*4 + uwave();
  if (v >= n) return;                         // uniform
  int cn = cnt[v];                            // scalar
  int c = min(cn, CAP);
  const int* row = adj + (size_t)v*CAP;
  int ureg = row[lane];                       // coalesced; pads = n
  int g = lane >> 4, q = lane & 15;
  float4 acc = {0.f, 0.f, 0.f, 0.f};
  int iters = (c + 3) >> 2;
  #pragma unroll 2
  for (int jj = 0; jj < iters; jj++){
    int u = __shfl(ureg, jj*4 + g);           // my group's row
    float4 tv = ((const float4*)(t + (size_t)u*64))[q];   // 16x16B = 256B/row
    acc.x += tv.x; acc.y += tv.y; acc.z += tv.z; acc.w += tv.w;
  }
  acc.x += __shfl_xor(acc.x, 16); acc.y += __shfl_xor(acc.y, 16);
  acc.z += __shfl_xor(acc.z, 16); acc.w += __shfl_xor(acc.w, 16);
  acc.x += __shfl_xor(acc.x, 32); acc.y += __shfl_xor(acc.y, 32);
  acc.z += __shfl_xor(acc.z, 32); acc.w += __shfl_xor(acc.w, 32);
  float dv = rsqrtf((float)cn);
  float4 bb = ((const float4*)b)[q];
  float4 res;
  res.x = fmaxf(fmaf(acc.x, dv, bb.x), 0.f);
  res.y = fmaxf(fmaf(acc.y, dv, bb.y), 0.f);
  res.z = fmaxf(fmaf(acc.z, dv, bb.z), 0.f);
  res.w = fmaxf(fmaf(acc.w, dv, bb.w), 0.f);
  if (lane < 16) ((float4*)(h + (size_t)v*64))[q] = res;  // 256B store
}

// GAT agg: softmax weights per edge, then grouped float4 gather like GCN.
__global__ __launch_bounds__(256) void k_gat_agg(const float* __restrict__ t,
                          const int* __restrict__ adj, const int* __restrict__ cnt,
                          const float* __restrict__ als, const float* __restrict__ ald,
                          const float* __restrict__ b, float* __restrict__ h, int n){
  int lane = threadIdx.x & 63;
  int v = blockIdx.x*4 + uwave();
  if (v >= n) return;
  int c = min(cnt[v], CAP);
  const int* row = adj + (size_t)v*CAP;
  int ureg = row[lane];                       // pads = n
  float adv = ald[v];                         // uniform
  float e = als[ureg] + adv;                  // 4B gather (pad lane masked below)
  e = e > 0.f ? e : 0.2f*e;
  float em = (lane < c) ? e : -1e30f;
  #pragma unroll
  for (int off = 32; off; off >>= 1) em = fmaxf(em, __shfl_xor(em, off));
  float p = (lane < c) ? __expf(e - em) : 0.f;
  float s = p;
  #pragma unroll
  for (int off = 32; off; off >>= 1) s += __shfl_xor(s, off);
  float inv = 1.f / s;
  int g = lane >> 4, q = lane & 15;
  float4 acc = {0.f, 0.f, 0.f, 0.f};
  int iters = (c + 3) >> 2;
  #pragma unroll 2
  for (int jj = 0; jj < iters; jj++){
    int   u = __shfl(ureg, jj*4 + g);
    float w = __shfl(p,    jj*4 + g);         // pad slots have p=0
    float4 tv = ((const float4*)(t + (size_t)u*64))[q];
    acc.x = fmaf(w, tv.x, acc.x); acc.y = fmaf(w, tv.y, acc.y);
    acc.z = fmaf(w, tv.z, acc.z); acc.w = fmaf(w, tv.w, acc.w);
  }
  acc.x += __shfl_xor(acc.x, 16); acc.y += __shfl_xor(acc.y, 16);
  acc.z += __shfl_xor(acc.z, 16); acc.w += __shfl_xor(acc.w, 16);
  acc.x += __shfl_xor(acc.x, 32); acc.y += __shfl_xor(acc.y, 32);
  acc.z += __shfl_xor(acc.z, 32); acc.w += __shfl_xor(acc.w, 32);
  float4 bb = ((const float4*)b)[q];
  float4 res;
  res.x = fmaxf(fmaf(acc.x, inv, bb.x), 0.f);
  res.y = fmaxf(fmaf(acc.y, inv, bb.y), 0.f);
  res.z = fmaxf(fmaf(acc.z, inv, bb.z), 0.f);
  res.w = fmaxf(fmaf(acc.w, inv, bb.w), 0.f);
  if (lane < 16) ((float4*)(h + (size_t)v*64))[q] = res;
}

// heads + mean partials: lane = concat col (0..9 opt | 32..63 bottleneck
// hidden); weights in VGPRs; per-block feature sums for the mean embedding.
__global__ __launch_bounds__(256, 4) void k_heads(const float* __restrict__ h,
                        const float* __restrict__ Wopt, const float* __restrict__ bopt,
                        const float* __restrict__ Wb1, const float* __restrict__ bb1,
                        const float* __restrict__ Wb2, const float* __restrict__ bb2,
                        float* __restrict__ out_opt, float* __restrict__ out_bot,
                        float* __restrict__ partial, int n){
  __shared__ float Wc[4096];
  __shared__ float bc[64];
  __shared__ float red[256];
  int tid = threadIdx.x;
  for (int i = tid; i < 4096; i += 256){
    int f = i >> 6, c = i & 63;
    float w = 0.f;
    if (c < 10)       w = Wopt[f*10 + c];
    else if (c >= 32) w = Wb1[f*32 + (c-32)];
    Wc[i] = w;
  }
  if (tid < 64){
    float bv = 0.f;
    if (tid < 10)       bv = bopt[tid];
    else if (tid >= 32) bv = bb1[tid-32];
    bc[tid] = bv;
  }
  __syncthreads();
  int lane = tid & 63;
  float wreg[64];
  #pragma unroll
  for (int f = 0; f < 64; f++) wreg[f] = Wc[f*64 + lane];  // once per wave
  float bcr  = bc[lane];
  float wb2r = (lane >= 32) ? Wb2[lane-32] : 0.f;
  float bb2r = bb2[0];
  int gw = blockIdx.x*4 + uwave();
  int nw = gridDim.x*4;
  float gacc = 0.f;
  for (int v = gw; v < n; v += nw){
    const float4* hr = (const float4*)(h + (size_t)v*64);
    float acc = bcr;
    #pragma unroll
    for (int f4 = 0; f4 < 16; f4++){
      float4 hv = hr[f4];
      acc = fmaf(hv.x, wreg[f4*4+0], acc);
      acc = fmaf(hv.y, wreg[f4*4+1], acc);
      acc = fmaf(hv.z, wreg[f4*4+2], acc);
      acc = fmaf(hv.w, wreg[f4*4+3], acc);
    }
    gacc += h[(size_t)v*64 + lane];           // coalesced, L2-hot (mean partial)
    if (lane < 10) out_opt[(size_t)v*10 + lane] = acc;
    float contrib = (lane >= 32) ? fmaxf(acc, 0.f) * wb2r : 0.f;
    #pragma unroll
    for (int off = 32; off; off >>= 1) contrib += __shfl_xor(contrib, off);
    if (lane == 0) out_bot[v] = 1.f / (1.f + __expf(-(contrib + bb2r)));
  }
  red[tid] = gacc;
  __syncthreads();
  if (tid < 64)
    partial[(size_t)blockIdx.x*64 + tid] = red[tid] + red[64+tid] + red[128+tid] + red[192+tid];
}

__global__ void k_embed(const float* __restrict__ partial, float* __restrict__ out_emb,
                        int nb, float invn){
  __shared__ float red[256];
  int tid = threadIdx.x;
  int lane = tid & 63, q = tid >> 6;
  float s = 0.f;
  for (int b = q; b < nb; b += 4) s += partial[(size_t)b*64 + lane];
  red[tid] = s;
  __syncthreads();
  if (tid < 64)
    out_emb[tid] = (red[tid] + red[64+tid] + red[128+tid] + red[192+tid]) * invn;
}

extern "C" void kernel_launch(void* const* d_in, const int* in_sizes, int n_in,
                              void* d_out, int out_size, void* d_ws, size_t ws_size,
                              hipStream_t stream) {
  const float* x    = (const float*)d_in[0];
  const int*   ei   = (const int*)d_in[1];
  const float* W1   = (const float*)d_in[2];
  const float* b1   = (const float*)d_in[3];
  const float* W2   = (const float*)d_in[4];
  const float* a_s  = (const float*)d_in[5];
  const float* a_d  = (const float*)d_in[6];
  const float* b2   = (const float*)d_in[7];
  const float* W3   = (const float*)d_in[8];
  const float* b3   = (const float*)d_in[9];
  const float* Wopt = (const float*)d_in[10];
  const float* bopt = (const float*)d_in[11];
  const float* Wb1  = (const float*)d_in[12];
  const float* bb1  = (const float*)d_in[13];
  const float* Wb2  = (const float*)d_in[14];
  const float* bb2  = (const float*)d_in[15];

  int n = in_sizes[0] / 32;      // 100000
  int e = in_sizes[1] / 2;       // 1250000
  const int* src = ei;
  const int* dst = ei + e;

  char* ws = (char*)d_ws;
  size_t off = 0;
  auto alloc = [&](size_t bytes) -> void* {
    void* p = ws + off;
    off += (bytes + 255) & ~(size_t)255;
    return p;
  };
  int*   cnt     = (int*)  alloc((size_t)n * 4);
  int*   adj     = (int*)  alloc((size_t)n * CAP * 4);
  float* als     = (float*)alloc((size_t)(n+64) * 4);     // +pad slot n
  float* ald     = (float*)alloc((size_t)n * 4);
  float* tbuf    = (float*)alloc((size_t)(n+1) * 64 * 4); // +zero row n
  float* hbuf    = (float*)alloc((size_t)n * 64 * 4);
  float* partial = (float*)alloc((size_t)1024 * 64 * 4);

  float* out_opt = (float*)d_out;
  float* out_bot = out_opt + (size_t)n * 10;
  float* out_emb = out_bot + n;

  int nbE  = (e + 255) / 256;
  int nb4  = (n + 3) / 4;
  int nper = (n + 7) / 8;

  k_init<<<nb4, 256, 0, stream>>>(cnt, adj, tbuf, n);
  k_hist<<<nbE*8, 256, 0, stream>>>(src, dst, cnt, adj, e, nper);

  // layer 1: GCN(32->64), t pre-scaled by rsqrt(cnt[v])
  k_gemm<32, true><<<1024, 256, 0, stream>>>(x, W1, cnt, tbuf, n);
  k_gcn_agg<<<nb4, 256, 0, stream>>>(tbuf, adj, cnt, b1, hbuf, n);

  // layer 2: GAT(64->64), unscaled
  k_gemm_alpha<<<1024, 256, 0, stream>>>(hbuf, W2, a_s, a_d, tbuf, als, ald, n);
  k_gat_agg<<<nb4, 256, 0, stream>>>(tbuf, adj, cnt, als, ald, b2, hbuf, n);

  // layer 3: GCN(64->64), pre-scaled
  k_gemm<64, true><<<1024, 256, 0, stream>>>(hbuf, W3, cnt, tbuf, n);
  k_gcn_agg<<<nb4, 256, 0, stream>>>(tbuf, adj, cnt, b3, hbuf, n);

  // heads + mean partials, then final embed reduce
  k_heads<<<1024, 256, 0, stream>>>(hbuf, Wopt, bopt, Wb1, bb1, Wb2, bb2,
                                    out_opt, out_bot, partial, n);
  k_embed<<<1, 256, 0, stream>>>(partial, out_emb, 1024, 1.0f / (float)n);
}

// Round 8
// 464.635 us; speedup vs baseline: 2.7515x; 1.1016x over previous
//
#include <hip/hip_runtime.h>
#include <hip/hip_bf16.h>

// WorkflowGNN: GCN(32->64)+ReLU, GAT(64->64,h=1)+ReLU, GCN(64->64)+ReLU,
// heads: opt [N,10], bottleneck [N,1], mean-embed [64]. f32 in/out.
// R7->R8: (1) pad-free adjacency: self-loop handled analytically in aggs
// (deg=cnt+1, GCN adds t[v], GAT adds p_self term); k_init no longer touches
// adj (was 25.6MB pad write + 25.6MB k_hist refetch). (2) k_embed was 64us:
// 1-block dependent load chain; replaced by 64-address atomicAdd from k_heads
// + trivial scale kernel. (3) aggs load adj exec-masked (lane<c only).

#define CAP 64

__device__ __forceinline__ int uwave(){                 // wave id, known-uniform
  return __builtin_amdgcn_readfirstlane(threadIdx.x >> 6);
}

// zero cnt; block 0 zeroes t pad row n and emb accumulator
__global__ void k_init(int* __restrict__ cnt, float* __restrict__ t,
                       float* __restrict__ emb_acc, int n){
  int v = blockIdx.x*blockDim.x + threadIdx.x;
  if (v < n) cnt[v] = 0;
  if (blockIdx.x == 0 && threadIdx.x < 64){
    t[(size_t)n*64 + threadIdx.x] = 0.f;
    emb_acc[threadIdx.x] = 0.f;
  }
}

// XCD-sliced histogram: slice = blockIdx&7 processes only dst in its range,
// so each XCD's atomics/scatter-writes stay in its own L2.
__global__ void k_hist(const int* __restrict__ src, const int* __restrict__ dst,
                       int* __restrict__ cnt, int* __restrict__ adj,
                       int e, int nper){
  int slice = blockIdx.x & 7;
  int i = (blockIdx.x >> 3)*blockDim.x + threadIdx.x;
  if (i >= e) return;
  int d = dst[i];
  int lo = slice*nper;
  if (d < lo || d >= lo + nper) return;
  int pos = atomicAdd(&cnt[d], 1);
  if (pos < CAP) adj[(size_t)d*CAP + pos] = src[i];
}

// t[v][lane] = (x[v] . W[:,lane]) * (SCALE ? rsqrt(cnt[v]+1) : 1)
template<int K, bool SCALE>
__global__ __launch_bounds__(256, 4) void k_gemm(const float* __restrict__ x,
                       const float* __restrict__ W, const int* __restrict__ cnt,
                       float* __restrict__ t, int n){
  int lane = threadIdx.x & 63;
  int gw = blockIdx.x*4 + uwave();
  int nw = gridDim.x*4;
  float wreg[K];
  #pragma unroll
  for (int k = 0; k < K; k++) wreg[k] = W[k*64 + lane];   // coalesced, once
  for (int v = gw; v < n; v += nw){                        // uniform loop
    const float4* xr = (const float4*)(x + (size_t)v*K);   // uniform row ptr
    float acc = 0.f;
    #pragma unroll
    for (int k4 = 0; k4 < K/4; k4++){
      float4 xv = xr[k4];                                  // scalarized
      acc = fmaf(xv.x, wreg[k4*4+0], acc);
      acc = fmaf(xv.y, wreg[k4*4+1], acc);
      acc = fmaf(xv.z, wreg[k4*4+2], acc);
      acc = fmaf(xv.w, wreg[k4*4+3], acc);
    }
    if (SCALE) acc *= rsqrtf((float)(cnt[v] + 1));         // uniform, deg=cnt+1
    t[(size_t)v*64 + lane] = acc;                          // coalesced 256B
  }
}

// K=64 GEMM (unscaled) + fused alpha_src/alpha_dst dots
__global__ __launch_bounds__(256, 4) void k_gemm_alpha(const float* __restrict__ x,
                       const float* __restrict__ W,
                       const float* __restrict__ asrc, const float* __restrict__ adst,
                       float* __restrict__ t, float* __restrict__ als,
                       float* __restrict__ ald, int n){
  int lane = threadIdx.x & 63;
  int gw = blockIdx.x*4 + uwave();
  int nw = gridDim.x*4;
  float wreg[64];
  #pragma unroll
  for (int k = 0; k < 64; k++) wreg[k] = W[k*64 + lane];
  float asr = asrc[lane], adr = adst[lane];
  for (int v = gw; v < n; v += nw){
    const float4* xr = (const float4*)(x + (size_t)v*64);
    float acc = 0.f;
    #pragma unroll
    for (int k4 = 0; k4 < 16; k4++){
      float4 xv = xr[k4];
      acc = fmaf(xv.x, wreg[k4*4+0], acc);
      acc = fmaf(xv.y, wreg[k4*4+1], acc);
      acc = fmaf(xv.z, wreg[k4*4+2], acc);
      acc = fmaf(xv.w, wreg[k4*4+3], acc);
    }
    t[(size_t)v*64 + lane] = acc;
    float s1 = acc * asr, s2 = acc * adr;
    #pragma unroll
    for (int off = 32; off; off >>= 1){
      s1 += __shfl_xor(s1, off);
      s2 += __shfl_xor(s2, off);
    }
    if (lane == 0){ als[v] = s1; ald[v] = s2; }
  }
}

// GCN agg: 4 groups x 16 lanes, one dwordx4 per lane = 4 rows per iteration.
// t pre-scaled by rsqrt(deg[u]); self-loop row t[v] added analytically.
__global__ __launch_bounds__(256) void k_gcn_agg(const float* __restrict__ t,
                          const int* __restrict__ adj, const int* __restrict__ cnt,
                          const float* __restrict__ b, float* __restrict__ h, int n){
  int lane = threadIdx.x & 63;
  int v = blockIdx.x*4 + uwave();
  if (v >= n) return;                         // uniform
  int cn = cnt[v];                            // scalar (real in-edges)
  int c = min(cn, CAP);
  const int* row = adj + (size_t)v*CAP;
  int ureg = n;                               // pad -> zero row
  if (lane < c) ureg = row[lane];             // exec-masked coalesced load
  int g = lane >> 4, q = lane & 15;
  float4 acc = {0.f, 0.f, 0.f, 0.f};
  int iters = (c + 3) >> 2;
  #pragma unroll 2
  for (int jj = 0; jj < iters; jj++){
    int u = __shfl(ureg, jj*4 + g);           // my group's row
    float4 tv = ((const float4*)(t + (size_t)u*64))[q];   // 16x16B = 256B/row
    acc.x += tv.x; acc.y += tv.y; acc.z += tv.z; acc.w += tv.w;
  }
  acc.x += __shfl_xor(acc.x, 16); acc.y += __shfl_xor(acc.y, 16);
  acc.z += __shfl_xor(acc.z, 16); acc.w += __shfl_xor(acc.w, 16);
  acc.x += __shfl_xor(acc.x, 32); acc.y += __shfl_xor(acc.y, 32);
  acc.z += __shfl_xor(acc.z, 32); acc.w += __shfl_xor(acc.w, 32);
  float4 selfv = ((const float4*)(t + (size_t)v*64))[q];  // self-loop (L2-hot)
  acc.x += selfv.x; acc.y += selfv.y; acc.z += selfv.z; acc.w += selfv.w;
  float dv = rsqrtf((float)(cn + 1));
  float4 bb = ((const float4*)b)[q];
  float4 res;
  res.x = fmaxf(fmaf(acc.x, dv, bb.x), 0.f);
  res.y = fmaxf(fmaf(acc.y, dv, bb.y), 0.f);
  res.z = fmaxf(fmaf(acc.z, dv, bb.z), 0.f);
  res.w = fmaxf(fmaf(acc.w, dv, bb.w), 0.f);
  if (lane < 16) ((float4*)(h + (size_t)v*64))[q] = res;  // 256B store
}

// GAT agg: softmax over real in-edges + analytic self-loop term.
__global__ __launch_bounds__(256) void k_gat_agg(const float* __restrict__ t,
                          const int* __restrict__ adj, const int* __restrict__ cnt,
                          const float* __restrict__ als, const float* __restrict__ ald,
                          const float* __restrict__ b, float* __restrict__ h, int n){
  int lane = threadIdx.x & 63;
  int v = blockIdx.x*4 + uwave();
  if (v >= n) return;
  int c = min(cnt[v], CAP);
  const int* row = adj + (size_t)v*CAP;
  int ureg = n;                               // pad -> zero row for gather
  if (lane < c) ureg = row[lane];
  int usafe = (lane < c) ? ureg : v;          // safe idx for als gather
  float adv = ald[v];                         // uniform
  float e = als[usafe] + adv;                 // 4B gather (lane=edge)
  e = e > 0.f ? e : 0.2f*e;
  float es = als[v] + adv;                    // self-loop score (uniform)
  es = es > 0.f ? es : 0.2f*es;
  float em = (lane < c) ? e : -1e30f;
  #pragma unroll
  for (int off = 32; off; off >>= 1) em = fmaxf(em, __shfl_xor(em, off));
  em = fmaxf(em, es);
  float p = (lane < c) ? __expf(e - em) : 0.f;
  float s = p;
  #pragma unroll
  for (int off = 32; off; off >>= 1) s += __shfl_xor(s, off);
  float ps = __expf(es - em);                 // self weight
  float inv = 1.f / (s + ps);
  int g = lane >> 4, q = lane & 15;
  float4 acc = {0.f, 0.f, 0.f, 0.f};
  int iters = (c + 3) >> 2;
  #pragma unroll 2
  for (int jj = 0; jj < iters; jj++){
    int   u = __shfl(ureg, jj*4 + g);
    float w = __shfl(p,    jj*4 + g);         // pad slots have p=0
    float4 tv = ((const float4*)(t + (size_t)u*64))[q];
    acc.x = fmaf(w, tv.x, acc.x); acc.y = fmaf(w, tv.y, acc.y);
    acc.z = fmaf(w, tv.z, acc.z); acc.w = fmaf(w, tv.w, acc.w);
  }
  acc.x += __shfl_xor(acc.x, 16); acc.y += __shfl_xor(acc.y, 16);
  acc.z += __shfl_xor(acc.z, 16); acc.w += __shfl_xor(acc.w, 16);
  acc.x += __shfl_xor(acc.x, 32); acc.y += __shfl_xor(acc.y, 32);
  acc.z += __shfl_xor(acc.z, 32); acc.w += __shfl_xor(acc.w, 32);
  float4 selfv = ((const float4*)(t + (size_t)v*64))[q];  // self row
  acc.x = fmaf(ps, selfv.x, acc.x); acc.y = fmaf(ps, selfv.y, acc.y);
  acc.z = fmaf(ps, selfv.z, acc.z); acc.w = fmaf(ps, selfv.w, acc.w);
  float4 bb = ((const float4*)b)[q];
  float4 res;
  res.x = fmaxf(fmaf(acc.x, inv, bb.x), 0.f);
  res.y = fmaxf(fmaf(acc.y, inv, bb.y), 0.f);
  res.z = fmaxf(fmaf(acc.z, inv, bb.z), 0.f);
  res.w = fmaxf(fmaf(acc.w, inv, bb.w), 0.f);
  if (lane < 16) ((float4*)(h + (size_t)v*64))[q] = res;
}

// heads + mean accumulation: lane = concat col (0..9 opt | 32..63 bottleneck
// hidden); weights in VGPRs; block feature-sums atomicAdd'ed to emb_acc[64].
__global__ __launch_bounds__(256, 4) void k_heads(const float* __restrict__ h,
                        const float* __restrict__ Wopt, const float* __restrict__ bopt,
                        const float* __restrict__ Wb1, const float* __restrict__ bb1,
                        const float* __restrict__ Wb2, const float* __restrict__ bb2,
                        float* __restrict__ out_opt, float* __restrict__ out_bot,
                        float* __restrict__ emb_acc, int n){
  __shared__ float Wc[4096];
  __shared__ float bc[64];
  __shared__ float red[256];
  int tid = threadIdx.x;
  for (int i = tid; i < 4096; i += 256){
    int f = i >> 6, c = i & 63;
    float w = 0.f;
    if (c < 10)       w = Wopt[f*10 + c];
    else if (c >= 32) w = Wb1[f*32 + (c-32)];
    Wc[i] = w;
  }
  if (tid < 64){
    float bv = 0.f;
    if (tid < 10)       bv = bopt[tid];
    else if (tid >= 32) bv = bb1[tid-32];
    bc[tid] = bv;
  }
  __syncthreads();
  int lane = tid & 63;
  float wreg[64];
  #pragma unroll
  for (int f = 0; f < 64; f++) wreg[f] = Wc[f*64 + lane];  // once per wave
  float bcr  = bc[lane];
  float wb2r = (lane >= 32) ? Wb2[lane-32] : 0.f;
  float bb2r = bb2[0];
  int gw = blockIdx.x*4 + uwave();
  int nw = gridDim.x*4;
  float gacc = 0.f;
  for (int v = gw; v < n; v += nw){
    const float4* hr = (const float4*)(h + (size_t)v*64);
    float acc = bcr;
    #pragma unroll
    for (int f4 = 0; f4 < 16; f4++){
      float4 hv = hr[f4];
      acc = fmaf(hv.x, wreg[f4*4+0], acc);
      acc = fmaf(hv.y, wreg[f4*4+1], acc);
      acc = fmaf(hv.z, wreg[f4*4+2], acc);
      acc = fmaf(hv.w, wreg[f4*4+3], acc);
    }
    gacc += h[(size_t)v*64 + lane];           // coalesced, L2-hot (mean partial)
    if (lane < 10) out_opt[(size_t)v*10 + lane] = acc;
    float contrib = (lane >= 32) ? fmaxf(acc, 0.f) * wb2r : 0.f;
    #pragma unroll
    for (int off = 32; off; off >>= 1) contrib += __shfl_xor(contrib, off);
    if (lane == 0) out_bot[v] = 1.f / (1.f + __expf(-(contrib + bb2r)));
  }
  red[tid] = gacc;
  __syncthreads();
  if (tid < 64)
    atomicAdd(&emb_acc[tid], red[tid] + red[64+tid] + red[128+tid] + red[192+tid]);
}

__global__ void k_embed(const float* __restrict__ emb_acc, float* __restrict__ out_emb,
                        float invn){
  if (threadIdx.x < 64) out_emb[threadIdx.x] = emb_acc[threadIdx.x] * invn;
}

extern "C" void kernel_launch(void* const* d_in, const int* in_sizes, int n_in,
                              void* d_out, int out_size, void* d_ws, size_t ws_size,
                              hipStream_t stream) {
  const float* x    = (const float*)d_in[0];
  const int*   ei   = (const int*)d_in[1];
  const float* W1   = (const float*)d_in[2];
  const float* b1   = (const float*)d_in[3];
  const float* W2   = (const float*)d_in[4];
  const float* a_s  = (const float*)d_in[5];
  const float* a_d  = (const float*)d_in[6];
  const float* b2   = (const float*)d_in[7];
  const float* W3   = (const float*)d_in[8];
  const float* b3   = (const float*)d_in[9];
  const float* Wopt = (const float*)d_in[10];
  const float* bopt = (const float*)d_in[11];
  const float* Wb1  = (const float*)d_in[12];
  const float* bb1  = (const float*)d_in[13];
  const float* Wb2  = (const float*)d_in[14];
  const float* bb2  = (const float*)d_in[15];

  int n = in_sizes[0] / 32;      // 100000
  int e = in_sizes[1] / 2;       // 1250000
  const int* src = ei;
  const int* dst = ei + e;

  char* ws = (char*)d_ws;
  size_t off = 0;
  auto alloc = [&](size_t bytes) -> void* {
    void* p = ws + off;
    off += (bytes + 255) & ~(size_t)255;
    return p;
  };
  int*   cnt     = (int*)  alloc((size_t)n * 4);
  int*   adj     = (int*)  alloc((size_t)n * CAP * 4);
  float* als     = (float*)alloc((size_t)n * 4);
  float* ald     = (float*)alloc((size_t)n * 4);
  float* tbuf    = (float*)alloc((size_t)(n+1) * 64 * 4); // +zero row n
  float* hbuf    = (float*)alloc((size_t)n * 64 * 4);
  float* emb_acc = (float*)alloc((size_t)64 * 4);

  float* out_opt = (float*)d_out;
  float* out_bot = out_opt + (size_t)n * 10;
  float* out_emb = out_bot + n;

  int nbN  = (n + 255) / 256;
  int nbE  = (e + 255) / 256;
  int nb4  = (n + 3) / 4;
  int nper = (n + 7) / 8;

  k_init<<<nbN, 256, 0, stream>>>(cnt, tbuf, emb_acc, n);
  k_hist<<<nbE*8, 256, 0, stream>>>(src, dst, cnt, adj, e, nper);

  // layer 1: GCN(32->64), t pre-scaled by rsqrt(deg)
  k_gemm<32, true><<<1024, 256, 0, stream>>>(x, W1, cnt, tbuf, n);
  k_gcn_agg<<<nb4, 256, 0, stream>>>(tbuf, adj, cnt, b1, hbuf, n);

  // layer 2: GAT(64->64), unscaled
  k_gemm_alpha<<<1024, 256, 0, stream>>>(hbuf, W2, a_s, a_d, tbuf, als, ald, n);
  k_gat_agg<<<nb4, 256, 0, stream>>>(tbuf, adj, cnt, als, ald, b2, hbuf, n);

  // layer 3: GCN(64->64), pre-scaled
  k_gemm<64, true><<<1024, 256, 0, stream>>>(hbuf, W3, cnt, tbuf, n);
  k_gcn_agg<<<nb4, 256, 0, stream>>>(tbuf, adj, cnt, b3, hbuf, n);

  // heads (+ mean via 64-address device atomics), then trivial scale
  k_heads<<<1024, 256, 0, stream>>>(hbuf, Wopt, bopt, Wb1, bb1, Wb2, bb2,
                                    out_opt, out_bot, emb_acc, n);
  k_embed<<<1, 64, 0, stream>>>(emb_acc, out_emb, 1.0f / (float)n);
}

// Round 9
// 453.484 us; speedup vs baseline: 2.8191x; 1.0246x over previous
//
#include <hip/hip_runtime.h>
#include <hip/hip_bf16.h>

// WorkflowGNN: GCN(32->64)+ReLU, GAT(64->64,h=1)+ReLU, GCN(64->64)+ReLU,
// heads: opt [N,10], bottleneck [N,1], mean-embed [64]. f32 in/out.
// R8->R9: (1) k_heads VGPR=44/LDS=17920 proved the compiler demoted wreg[64]
// to per-FMA ds_read (59us LDS-issue floor = measured 64us). Weights now load
// straight from global into VGPRs, zero LDS staging. (2) k_hist adj scatter
// uses nontemporal stores (kill RFO + dirty-sector churn). (3) layer-1 GCN
// swapped to aggregate-then-transform: gather 128B x-rows weighted by
// rsqrt(deg_u), then gemm32 with fused bias+relu; y reuses tbuf (stride 32).

#define CAP 64

__device__ __forceinline__ int uwave(){                 // wave id, known-uniform
  return __builtin_amdgcn_readfirstlane(threadIdx.x >> 6);
}

// zero cnt; block 0 zeroes t pad row n and emb accumulator
__global__ void k_init(int* __restrict__ cnt, float* __restrict__ t,
                       float* __restrict__ emb_acc, int n){
  int v = blockIdx.x*blockDim.x + threadIdx.x;
  if (v < n) cnt[v] = 0;
  if (blockIdx.x == 0 && threadIdx.x < 64){
    t[(size_t)n*64 + threadIdx.x] = 0.f;
    emb_acc[threadIdx.x] = 0.f;
  }
}

// XCD-sliced histogram; adj scatter via nontemporal store (no RFO/L2 dirty).
__global__ void k_hist(const int* __restrict__ src, const int* __restrict__ dst,
                       int* __restrict__ cnt, int* __restrict__ adj,
                       int e, int nper){
  int slice = blockIdx.x & 7;
  int i = (blockIdx.x >> 3)*blockDim.x + threadIdx.x;
  if (i >= e) return;
  int d = dst[i];
  int lo = slice*nper;
  if (d < lo || d >= lo + nper) return;
  int pos = atomicAdd(&cnt[d], 1);
  if (pos < CAP){
    int sv = src[i];
    __builtin_nontemporal_store(sv, &adj[(size_t)d*CAP + pos]);
  }
}

// layer-1 aggregate in INPUT space: y[v] = dinv_v * (sum_u dinv_u*x[u] + dinv_v*x[v])
// 8 groups x 8 lanes: one dwordx4/lane = 8 rows (128B each) per iteration.
__global__ __launch_bounds__(256) void k_agg32(const float* __restrict__ x,
                          const int* __restrict__ adj, const int* __restrict__ cnt,
                          float* __restrict__ y, int n){
  int lane = threadIdx.x & 63;
  int v = blockIdx.x*4 + uwave();
  if (v >= n) return;                         // uniform
  int cn = cnt[v];
  int c = min(cn, CAP);
  const int* row = adj + (size_t)v*CAP;
  int usafe = v;
  if (lane < c) usafe = row[lane];            // exec-masked coalesced
  float wl = (lane < c) ? rsqrtf((float)(cnt[usafe] + 1)) : 0.f;  // dinv_u
  int g = lane >> 3, q = lane & 7;
  float4 acc = {0.f, 0.f, 0.f, 0.f};
  int iters = (c + 7) >> 3;
  for (int jj = 0; jj < iters; jj++){
    int   u = __shfl(usafe, jj*8 + g);
    float w = __shfl(wl,    jj*8 + g);        // pad lanes weight 0
    float4 tv = ((const float4*)(x + (size_t)u*32))[q];   // 8x16B = 128B/row
    acc.x = fmaf(w, tv.x, acc.x); acc.y = fmaf(w, tv.y, acc.y);
    acc.z = fmaf(w, tv.z, acc.z); acc.w = fmaf(w, tv.w, acc.w);
  }
  #pragma unroll
  for (int off = 8; off <= 32; off <<= 1){
    acc.x += __shfl_xor(acc.x, off); acc.y += __shfl_xor(acc.y, off);
    acc.z += __shfl_xor(acc.z, off); acc.w += __shfl_xor(acc.w, off);
  }
  float dv = rsqrtf((float)(cn + 1));
  float4 sv = ((const float4*)(x + (size_t)v*32))[q];     // self row
  acc.x = fmaf(dv, sv.x, acc.x); acc.y = fmaf(dv, sv.y, acc.y);
  acc.z = fmaf(dv, sv.z, acc.z); acc.w = fmaf(dv, sv.w, acc.w);
  float4 res = {acc.x*dv, acc.y*dv, acc.z*dv, acc.w*dv};
  if (lane < 8) ((float4*)(y + (size_t)v*32))[q] = res;   // 128B store
}

// t[v][lane] = (x[v] . W[:,lane]) * (SCALE ? rsqrt(cnt[v]+1) : 1)
// BRELU: t = relu(dot + b[lane])  (used when gemm is a layer's last op)
template<int K, bool SCALE, bool BRELU>
__global__ __launch_bounds__(256, 4) void k_gemm(const float* __restrict__ x,
                       const float* __restrict__ W, const int* __restrict__ cnt,
                       const float* __restrict__ b, float* __restrict__ t, int n){
  int lane = threadIdx.x & 63;
  int gw = blockIdx.x*4 + uwave();
  int nw = gridDim.x*4;
  float wreg[K];
  #pragma unroll
  for (int k = 0; k < K; k++) wreg[k] = W[k*64 + lane];   // coalesced, once
  float br = BRELU ? b[lane] : 0.f;
  for (int v = gw; v < n; v += nw){                        // uniform loop
    const float4* xr = (const float4*)(x + (size_t)v*K);   // uniform row ptr
    float acc = 0.f;
    #pragma unroll
    for (int k4 = 0; k4 < K/4; k4++){
      float4 xv = xr[k4];                                  // scalarized
      acc = fmaf(xv.x, wreg[k4*4+0], acc);
      acc = fmaf(xv.y, wreg[k4*4+1], acc);
      acc = fmaf(xv.z, wreg[k4*4+2], acc);
      acc = fmaf(xv.w, wreg[k4*4+3], acc);
    }
    if (SCALE) acc *= rsqrtf((float)(cnt[v] + 1));         // uniform, deg=cnt+1
    if (BRELU) acc = fmaxf(acc + br, 0.f);
    t[(size_t)v*64 + lane] = acc;                          // coalesced 256B
  }
}

// K=64 GEMM (unscaled) + fused alpha_src/alpha_dst dots
__global__ __launch_bounds__(256, 4) void k_gemm_alpha(const float* __restrict__ x,
                       const float* __restrict__ W,
                       const float* __restrict__ asrc, const float* __restrict__ adst,
                       float* __restrict__ t, float* __restrict__ als,
                       float* __restrict__ ald, int n){
  int lane = threadIdx.x & 63;
  int gw = blockIdx.x*4 + uwave();
  int nw = gridDim.x*4;
  float wreg[64];
  #pragma unroll
  for (int k = 0; k < 64; k++) wreg[k] = W[k*64 + lane];
  float asr = asrc[lane], adr = adst[lane];
  for (int v = gw; v < n; v += nw){
    const float4* xr = (const float4*)(x + (size_t)v*64);
    float acc = 0.f;
    #pragma unroll
    for (int k4 = 0; k4 < 16; k4++){
      float4 xv = xr[k4];
      acc = fmaf(xv.x, wreg[k4*4+0], acc);
      acc = fmaf(xv.y, wreg[k4*4+1], acc);
      acc = fmaf(xv.z, wreg[k4*4+2], acc);
      acc = fmaf(xv.w, wreg[k4*4+3], acc);
    }
    t[(size_t)v*64 + lane] = acc;
    float s1 = acc * asr, s2 = acc * adr;
    #pragma unroll
    for (int off = 32; off; off >>= 1){
      s1 += __shfl_xor(s1, off);
      s2 += __shfl_xor(s2, off);
    }
    if (lane == 0){ als[v] = s1; ald[v] = s2; }
  }
}

// GCN agg (layer 3): 4 groups x 16 lanes, dwordx4 = 4 rows (256B) per iter.
// t pre-scaled by rsqrt(deg[u]); self-loop row t[v] added analytically.
__global__ __launch_bounds__(256) void k_gcn_agg(const float* __restrict__ t,
                          const int* __restrict__ adj, const int* __restrict__ cnt,
                          const float* __restrict__ b, float* __restrict__ h, int n){
  int lane = threadIdx.x & 63;
  int v = blockIdx.x*4 + uwave();
  if (v >= n) return;                         // uniform
  int cn = cnt[v];                            // scalar (real in-edges)
  int c = min(cn, CAP);
  const int* row = adj + (size_t)v*CAP;
  int ureg = n;                               // pad -> zero row
  if (lane < c) ureg = row[lane];             // exec-masked coalesced load
  int g = lane >> 4, q = lane & 15;
  float4 acc = {0.f, 0.f, 0.f, 0.f};
  int iters = (c + 3) >> 2;
  #pragma unroll 2
  for (int jj = 0; jj < iters; jj++){
    int u = __shfl(ureg, jj*4 + g);           // my group's row
    float4 tv = ((const float4*)(t + (size_t)u*64))[q];   // 16x16B = 256B/row
    acc.x += tv.x; acc.y += tv.y; acc.z += tv.z; acc.w += tv.w;
  }
  acc.x += __shfl_xor(acc.x, 16); acc.y += __shfl_xor(acc.y, 16);
  acc.z += __shfl_xor(acc.z, 16); acc.w += __shfl_xor(acc.w, 16);
  acc.x += __shfl_xor(acc.x, 32); acc.y += __shfl_xor(acc.y, 32);
  acc.z += __shfl_xor(acc.z, 32); acc.w += __shfl_xor(acc.w, 32);
  float4 selfv = ((const float4*)(t + (size_t)v*64))[q];  // self-loop (L2-hot)
  acc.x += selfv.x; acc.y += selfv.y; acc.z += selfv.z; acc.w += selfv.w;
  float dv = rsqrtf((float)(cn + 1));
  float4 bb = ((const float4*)b)[q];
  float4 res;
  res.x = fmaxf(fmaf(acc.x, dv, bb.x), 0.f);
  res.y = fmaxf(fmaf(acc.y, dv, bb.y), 0.f);
  res.z = fmaxf(fmaf(acc.z, dv, bb.z), 0.f);
  res.w = fmaxf(fmaf(acc.w, dv, bb.w), 0.f);
  if (lane < 16) ((float4*)(h + (size_t)v*64))[q] = res;  // 256B store
}

// GAT agg: softmax over real in-edges + analytic self-loop term.
__global__ __launch_bounds__(256) void k_gat_agg(const float* __restrict__ t,
                          const int* __restrict__ adj, const int* __restrict__ cnt,
                          const float* __restrict__ als, const float* __restrict__ ald,
                          const float* __restrict__ b, float* __restrict__ h, int n){
  int lane = threadIdx.x & 63;
  int v = blockIdx.x*4 + uwave();
  if (v >= n) return;
  int c = min(cnt[v], CAP);
  const int* row = adj + (size_t)v*CAP;
  int ureg = n;                               // pad -> zero row for gather
  if (lane < c) ureg = row[lane];
  int usafe = (lane < c) ? ureg : v;          // safe idx for als gather
  float adv = ald[v];                         // uniform
  float e = als[usafe] + adv;                 // 4B gather (lane=edge)
  e = e > 0.f ? e : 0.2f*e;
  float es = als[v] + adv;                    // self-loop score (uniform)
  es = es > 0.f ? es : 0.2f*es;
  float em = (lane < c) ? e : -1e30f;
  #pragma unroll
  for (int off = 32; off; off >>= 1) em = fmaxf(em, __shfl_xor(em, off));
  em = fmaxf(em, es);
  float p = (lane < c) ? __expf(e - em) : 0.f;
  float s = p;
  #pragma unroll
  for (int off = 32; off; off >>= 1) s += __shfl_xor(s, off);
  float ps = __expf(es - em);                 // self weight
  float inv = 1.f / (s + ps);
  int g = lane >> 4, q = lane & 15;
  float4 acc = {0.f, 0.f, 0.f, 0.f};
  int iters = (c + 3) >> 2;
  #pragma unroll 2
  for (int jj = 0; jj < iters; jj++){
    int   u = __shfl(ureg, jj*4 + g);
    float w = __shfl(p,    jj*4 + g);         // pad slots have p=0
    float4 tv = ((const float4*)(t + (size_t)u*64))[q];
    acc.x = fmaf(w, tv.x, acc.x); acc.y = fmaf(w, tv.y, acc.y);
    acc.z = fmaf(w, tv.z, acc.z); acc.w = fmaf(w, tv.w, acc.w);
  }
  acc.x += __shfl_xor(acc.x, 16); acc.y += __shfl_xor(acc.y, 16);
  acc.z += __shfl_xor(acc.z, 16); acc.w += __shfl_xor(acc.w, 16);
  acc.x += __shfl_xor(acc.x, 32); acc.y += __shfl_xor(acc.y, 32);
  acc.z += __shfl_xor(acc.z, 32); acc.w += __shfl_xor(acc.w, 32);
  float4 selfv = ((const float4*)(t + (size_t)v*64))[q];  // self row
  acc.x = fmaf(ps, selfv.x, acc.x); acc.y = fmaf(ps, selfv.y, acc.y);
  acc.z = fmaf(ps, selfv.z, acc.z); acc.w = fmaf(ps, selfv.w, acc.w);
  float4 bb = ((const float4*)b)[q];
  float4 res;
  res.x = fmaxf(fmaf(acc.x, inv, bb.x), 0.f);
  res.y = fmaxf(fmaf(acc.y, inv, bb.y), 0.f);
  res.z = fmaxf(fmaf(acc.z, inv, bb.z), 0.f);
  res.w = fmaxf(fmaf(acc.w, inv, bb.w), 0.f);
  if (lane < 16) ((float4*)(h + (size_t)v*64))[q] = res;
}

// heads + mean accumulation: lane = concat col (0..9 opt | 32..63 bottleneck
// hidden); weights loaded from GLOBAL into VGPRs (no LDS -> no ds_read
// demotion); block feature-sums atomicAdd'ed to emb_acc[64].
__global__ __launch_bounds__(256, 4) void k_heads(const float* __restrict__ h,
                        const float* __restrict__ Wopt, const float* __restrict__ bopt,
                        const float* __restrict__ Wb1, const float* __restrict__ bb1,
                        const float* __restrict__ Wb2, const float* __restrict__ bb2,
                        float* __restrict__ out_opt, float* __restrict__ out_bot,
                        float* __restrict__ emb_acc, int n){
  __shared__ float red[256];
  int tid = threadIdx.x;
  int lane = tid & 63;
  float wreg[64];
  #pragma unroll
  for (int f = 0; f < 64; f++){
    float w = 0.f;
    if (lane < 10)       w = Wopt[f*10 + lane];
    else if (lane >= 32) w = Wb1[f*32 + (lane-32)];
    wreg[f] = w;                               // strided global, once per wave
  }
  float bcr = 0.f;
  if (lane < 10)       bcr = bopt[lane];
  else if (lane >= 32) bcr = bb1[lane-32];
  float wb2r = (lane >= 32) ? Wb2[lane-32] : 0.f;
  float bb2r = bb2[0];
  int gw = blockIdx.x*4 + uwave();
  int nw = gridDim.x*4;
  float gacc = 0.f;
  for (int v = gw; v < n; v += nw){
    const float4* hr = (const float4*)(h + (size_t)v*64);
    float acc = bcr;
    #pragma unroll
    for (int f4 = 0; f4 < 16; f4++){
      float4 hv = hr[f4];
      acc = fmaf(hv.x, wreg[f4*4+0], acc);
      acc = fmaf(hv.y, wreg[f4*4+1], acc);
      acc = fmaf(hv.z, wreg[f4*4+2], acc);
      acc = fmaf(hv.w, wreg[f4*4+3], acc);
    }
    gacc += h[(size_t)v*64 + lane];           // coalesced, L2-hot (mean partial)
    if (lane < 10) out_opt[(size_t)v*10 + lane] = acc;
    float contrib = (lane >= 32) ? fmaxf(acc, 0.f) * wb2r : 0.f;
    #pragma unroll
    for (int off = 32; off; off >>= 1) contrib += __shfl_xor(contrib, off);
    if (lane == 0) out_bot[v] = 1.f / (1.f + __expf(-(contrib + bb2r)));
  }
  red[tid] = gacc;
  __syncthreads();
  if (tid < 64)
    atomicAdd(&emb_acc[tid], red[tid] + red[64+tid] + red[128+tid] + red[192+tid]);
}

__global__ void k_embed(const float* __restrict__ emb_acc, float* __restrict__ out_emb,
                        float invn){
  if (threadIdx.x < 64) out_emb[threadIdx.x] = emb_acc[threadIdx.x] * invn;
}

extern "C" void kernel_launch(void* const* d_in, const int* in_sizes, int n_in,
                              void* d_out, int out_size, void* d_ws, size_t ws_size,
                              hipStream_t stream) {
  const float* x    = (const float*)d_in[0];
  const int*   ei   = (const int*)d_in[1];
  const float* W1   = (const float*)d_in[2];
  const float* b1   = (const float*)d_in[3];
  const float* W2   = (const float*)d_in[4];
  const float* a_s  = (const float*)d_in[5];
  const float* a_d  = (const float*)d_in[6];
  const float* b2   = (const float*)d_in[7];
  const float* W3   = (const float*)d_in[8];
  const float* b3   = (const float*)d_in[9];
  const float* Wopt = (const float*)d_in[10];
  const float* bopt = (const float*)d_in[11];
  const float* Wb1  = (const float*)d_in[12];
  const float* bb1  = (const float*)d_in[13];
  const float* Wb2  = (const float*)d_in[14];
  const float* bb2  = (const float*)d_in[15];

  int n = in_sizes[0] / 32;      // 100000
  int e = in_sizes[1] / 2;       // 1250000
  const int* src = ei;
  const int* dst = ei + e;

  char* ws = (char*)d_ws;
  size_t off = 0;
  auto alloc = [&](size_t bytes) -> void* {
    void* p = ws + off;
    off += (bytes + 255) & ~(size_t)255;
    return p;
  };
  int*   cnt     = (int*)  alloc((size_t)n * 4);
  int*   adj     = (int*)  alloc((size_t)n * CAP * 4);
  float* als     = (float*)alloc((size_t)n * 4);
  float* ald     = (float*)alloc((size_t)n * 4);
  float* tbuf    = (float*)alloc((size_t)(n+1) * 64 * 4); // +zero row n
  float* hbuf    = (float*)alloc((size_t)n * 64 * 4);
  float* emb_acc = (float*)alloc((size_t)64 * 4);

  float* out_opt = (float*)d_out;
  float* out_bot = out_opt + (size_t)n * 10;
  float* out_emb = out_bot + n;

  int nbN  = (n + 255) / 256;
  int nbE  = (e + 255) / 256;
  int nb4  = (n + 3) / 4;
  int nper = (n + 7) / 8;

  k_init<<<nbN, 256, 0, stream>>>(cnt, tbuf, emb_acc, n);
  k_hist<<<nbE*8, 256, 0, stream>>>(src, dst, cnt, adj, e, nper);

  // layer 1: GCN(32->64) swapped: aggregate x (128B rows) into tbuf (stride
  // 32), then gemm with fused bias+relu -> hbuf
  k_agg32<<<nb4, 256, 0, stream>>>(x, adj, cnt, tbuf, n);
  k_gemm<32, false, true><<<1024, 256, 0, stream>>>(tbuf, W1, cnt, b1, hbuf, n);

  // layer 2: GAT(64->64), unscaled
  k_gemm_alpha<<<1024, 256, 0, stream>>>(hbuf, W2, a_s, a_d, tbuf, als, ald, n);
  k_gat_agg<<<nb4, 256, 0, stream>>>(tbuf, adj, cnt, als, ald, b2, hbuf, n);

  // layer 3: GCN(64->64), pre-scaled by rsqrt(deg)
  k_gemm<64, true, false><<<1024, 256, 0, stream>>>(hbuf, W3, cnt, b3, tbuf, n);
  k_gcn_agg<<<nb4, 256, 0, stream>>>(tbuf, adj, cnt, b3, hbuf, n);

  // heads (+ mean via 64-address device atomics), then trivial scale
  k_heads<<<1024, 256, 0, stream>>>(hbuf, Wopt, bopt, Wb1, bb1, Wb2, bb2,
                                    out_opt, out_bot, emb_acc, n);
  k_embed<<<1, 64, 0, stream>>>(emb_acc, out_emb, 1.0f / (float)n);
}

// Round 10
// 435.258 us; speedup vs baseline: 2.9372x; 1.0419x over previous
//
#include <hip/hip_runtime.h>
#include <hip/hip_bf16.h>

// WorkflowGNN: GCN(32->64)+ReLU, GAT(64->64,h=1)+ReLU, GCN(64->64)+ReLU,
// heads: opt [N,10], bottleneck [N,1], mean-embed [64]. f32 in/out.
// R9->R10: (1) bf16 gather buffers: random row-gathers dominate (gat FETCH
// 162MB); x cast to bf16 (64B rows), t2/t3 stored bf16 by the gemms (128B
// rows) -> gather bytes halved, 8 rows per vmem instruction (8 grp x 8 lanes).
// Scores als/ald stay f32. Threshold is bf16-scaled (1.02e-2), 20x headroom.
// (2) k_hist: nt LOADS for edge stream (keep adj window in L2), plain store.
// (3) y1 aliases tb; no workspace growth.

#define CAP 64

__device__ __forceinline__ int uwave(){                 // wave id, known-uniform
  return __builtin_amdgcn_readfirstlane(threadIdx.x >> 6);
}
__device__ __forceinline__ unsigned short f2bf(float f){ // RNE, finite inputs
  unsigned u = __float_as_uint(f);
  return (unsigned short)((u + 0x7fffu + ((u >> 16) & 1u)) >> 16);
}
__device__ __forceinline__ float bfl(unsigned u){ return __uint_as_float(u << 16); }
__device__ __forceinline__ float bfh(unsigned u){ return __uint_as_float(u & 0xffff0000u); }

// zero cnt; block 0 zeroes bf16 t pad row n and emb accumulator
__global__ void k_init(int* __restrict__ cnt, unsigned short* __restrict__ tb,
                       float* __restrict__ emb_acc, int n){
  int v = blockIdx.x*blockDim.x + threadIdx.x;
  if (v < n) cnt[v] = 0;
  if (blockIdx.x == 0 && threadIdx.x < 64){
    tb[(size_t)n*64 + threadIdx.x] = 0;
    emb_acc[threadIdx.x] = 0.f;
  }
}

// cast x [n*32] f32 -> bf16 (gather source for layer 1)
__global__ void k_cast(const float* __restrict__ x, unsigned short* __restrict__ xh,
                       int total4){
  int i = blockIdx.x*blockDim.x + threadIdx.x;
  if (i >= total4) return;
  float4 v = ((const float4*)x)[i];
  uint2 o;
  o.x = (unsigned)f2bf(v.x) | ((unsigned)f2bf(v.y) << 16);
  o.y = (unsigned)f2bf(v.z) | ((unsigned)f2bf(v.w) << 16);
  ((uint2*)xh)[i] = o;
}

// XCD-sliced histogram; edge stream via nontemporal loads (no L2 pollution),
// adj scatter plain store (coalesces in the per-XCD L2 window).
__global__ void k_hist(const int* __restrict__ src, const int* __restrict__ dst,
                       int* __restrict__ cnt, int* __restrict__ adj,
                       int e, int nper){
  int slice = blockIdx.x & 7;
  int i = (blockIdx.x >> 3)*blockDim.x + threadIdx.x;
  if (i >= e) return;
  int d = __builtin_nontemporal_load(&dst[i]);
  int lo = slice*nper;
  if (d < lo || d >= lo + nper) return;
  int pos = atomicAdd(&cnt[d], 1);
  if (pos < CAP){
    int sv = __builtin_nontemporal_load(&src[i]);
    adj[(size_t)d*CAP + pos] = sv;
  }
}

// layer-1 aggregate in INPUT space (bf16 x, 64B rows): 8 grp x 8 lanes,
// uint2/lane = 8 rows per instruction. y = dinv_v*(sum dinv_u*x[u] + dinv_v*x[v])
__global__ __launch_bounds__(256) void k_agg32(const unsigned short* __restrict__ xh,
                          const int* __restrict__ adj, const int* __restrict__ cnt,
                          float* __restrict__ y, int n){
  int lane = threadIdx.x & 63;
  int v = blockIdx.x*4 + uwave();
  if (v >= n) return;                         // uniform
  int cn = cnt[v];
  int c = min(cn, CAP);
  const int* row = adj + (size_t)v*CAP;
  int usafe = v;
  if (lane < c) usafe = row[lane];            // exec-masked coalesced
  float wl = (lane < c) ? rsqrtf((float)(cnt[usafe] + 1)) : 0.f;  // dinv_u
  int g = lane >> 3, q = lane & 7;
  float4 acc = {0.f, 0.f, 0.f, 0.f};
  int iters = (c + 7) >> 3;
  for (int jj = 0; jj < iters; jj++){
    int   u = __shfl(usafe, jj*8 + g);
    float w = __shfl(wl,    jj*8 + g);        // pad lanes weight 0
    uint2 r = ((const uint2*)(xh + (size_t)u*32))[q];     // 8B = 4 bf16
    acc.x = fmaf(w, bfl(r.x), acc.x); acc.y = fmaf(w, bfh(r.x), acc.y);
    acc.z = fmaf(w, bfl(r.y), acc.z); acc.w = fmaf(w, bfh(r.y), acc.w);
  }
  #pragma unroll
  for (int off = 8; off <= 32; off <<= 1){
    acc.x += __shfl_xor(acc.x, off); acc.y += __shfl_xor(acc.y, off);
    acc.z += __shfl_xor(acc.z, off); acc.w += __shfl_xor(acc.w, off);
  }
  float dv = rsqrtf((float)(cn + 1));
  uint2 sr = ((const uint2*)(xh + (size_t)v*32))[q];      // self row
  acc.x = fmaf(dv, bfl(sr.x), acc.x); acc.y = fmaf(dv, bfh(sr.x), acc.y);
  acc.z = fmaf(dv, bfl(sr.y), acc.z); acc.w = fmaf(dv, bfh(sr.y), acc.w);
  float4 res = {acc.x*dv, acc.y*dv, acc.z*dv, acc.w*dv};
  if (lane < 8) ((float4*)(y + (size_t)v*32))[q] = res;   // 128B store
}

// t[v][lane] = relu?(x[v].W[:,lane] * scale? + b?) -> f32 out (layer outputs)
template<int K, bool SCALE, bool BRELU>
__global__ __launch_bounds__(256, 4) void k_gemm(const float* __restrict__ x,
                       const float* __restrict__ W, const int* __restrict__ cnt,
                       const float* __restrict__ b, float* __restrict__ t, int n){
  int lane = threadIdx.x & 63;
  int gw = blockIdx.x*4 + uwave();
  int nw = gridDim.x*4;
  float wreg[K];
  #pragma unroll
  for (int k = 0; k < K; k++) wreg[k] = W[k*64 + lane];   // coalesced, once
  float br = BRELU ? b[lane] : 0.f;
  for (int v = gw; v < n; v += nw){                        // uniform loop
    const float4* xr = (const float4*)(x + (size_t)v*K);
    float acc = 0.f;
    #pragma unroll
    for (int k4 = 0; k4 < K/4; k4++){
      float4 xv = xr[k4];                                  // scalarized
      acc = fmaf(xv.x, wreg[k4*4+0], acc);
      acc = fmaf(xv.y, wreg[k4*4+1], acc);
      acc = fmaf(xv.z, wreg[k4*4+2], acc);
      acc = fmaf(xv.w, wreg[k4*4+3], acc);
    }
    if (SCALE) acc *= rsqrtf((float)(cnt[v] + 1));
    if (BRELU) acc = fmaxf(acc + br, 0.f);
    t[(size_t)v*64 + lane] = acc;
  }
}

// K=64 GEMM -> bf16 out (gather source), optional pre-scale by rsqrt(deg)
template<bool SCALE>
__global__ __launch_bounds__(256, 4) void k_gemm_b(const float* __restrict__ x,
                       const float* __restrict__ W, const int* __restrict__ cnt,
                       unsigned short* __restrict__ t, int n){
  int lane = threadIdx.x & 63;
  int gw = blockIdx.x*4 + uwave();
  int nw = gridDim.x*4;
  float wreg[64];
  #pragma unroll
  for (int k = 0; k < 64; k++) wreg[k] = W[k*64 + lane];
  for (int v = gw; v < n; v += nw){
    const float4* xr = (const float4*)(x + (size_t)v*64);
    float acc = 0.f;
    #pragma unroll
    for (int k4 = 0; k4 < 16; k4++){
      float4 xv = xr[k4];
      acc = fmaf(xv.x, wreg[k4*4+0], acc);
      acc = fmaf(xv.y, wreg[k4*4+1], acc);
      acc = fmaf(xv.z, wreg[k4*4+2], acc);
      acc = fmaf(xv.w, wreg[k4*4+3], acc);
    }
    if (SCALE) acc *= rsqrtf((float)(cnt[v] + 1));
    t[(size_t)v*64 + lane] = f2bf(acc);                    // 128B coalesced
  }
}

// K=64 GEMM -> bf16 out + fused alpha_src/alpha_dst dots (f32 scores)
__global__ __launch_bounds__(256, 4) void k_gemm_alpha(const float* __restrict__ x,
                       const float* __restrict__ W,
                       const float* __restrict__ asrc, const float* __restrict__ adst,
                       unsigned short* __restrict__ t, float* __restrict__ als,
                       float* __restrict__ ald, int n){
  int lane = threadIdx.x & 63;
  int gw = blockIdx.x*4 + uwave();
  int nw = gridDim.x*4;
  float wreg[64];
  #pragma unroll
  for (int k = 0; k < 64; k++) wreg[k] = W[k*64 + lane];
  float asr = asrc[lane], adr = adst[lane];
  for (int v = gw; v < n; v += nw){
    const float4* xr = (const float4*)(x + (size_t)v*64);
    float acc = 0.f;
    #pragma unroll
    for (int k4 = 0; k4 < 16; k4++){
      float4 xv = xr[k4];
      acc = fmaf(xv.x, wreg[k4*4+0], acc);
      acc = fmaf(xv.y, wreg[k4*4+1], acc);
      acc = fmaf(xv.z, wreg[k4*4+2], acc);
      acc = fmaf(xv.w, wreg[k4*4+3], acc);
    }
    t[(size_t)v*64 + lane] = f2bf(acc);
    float s1 = acc * asr, s2 = acc * adr;
    #pragma unroll
    for (int off = 32; off; off >>= 1){
      s1 += __shfl_xor(s1, off);
      s2 += __shfl_xor(s2, off);
    }
    if (lane == 0){ als[v] = s1; ald[v] = s2; }
  }
}

// GCN agg (layer 3), bf16 rows: 8 grp x 8 lanes, uint4/lane = 8 rows/instr.
// t pre-scaled by rsqrt(deg[u]); self row added; bias+relu fused.
__global__ __launch_bounds__(256) void k_gcn_agg(const unsigned short* __restrict__ t,
                          const int* __restrict__ adj, const int* __restrict__ cnt,
                          const float* __restrict__ b, float* __restrict__ h, int n){
  int lane = threadIdx.x & 63;
  int v = blockIdx.x*4 + uwave();
  if (v >= n) return;                         // uniform
  int cn = cnt[v];
  int c = min(cn, CAP);
  const int* row = adj + (size_t)v*CAP;
  int ureg = n;                               // pad -> zero row
  if (lane < c) ureg = row[lane];
  int g = lane >> 3, q = lane & 7;
  float acc[8] = {0.f,0.f,0.f,0.f,0.f,0.f,0.f,0.f};
  int iters = (c + 7) >> 3;
  for (int jj = 0; jj < iters; jj++){
    int u = __shfl(ureg, jj*8 + g);
    uint4 r = ((const uint4*)(t + (size_t)u*64))[q];      // 16B = 8 bf16
    acc[0] += bfl(r.x); acc[1] += bfh(r.x); acc[2] += bfl(r.y); acc[3] += bfh(r.y);
    acc[4] += bfl(r.z); acc[5] += bfh(r.z); acc[6] += bfl(r.w); acc[7] += bfh(r.w);
  }
  #pragma unroll
  for (int off = 8; off <= 32; off <<= 1){
    #pragma unroll
    for (int k = 0; k < 8; k++) acc[k] += __shfl_xor(acc[k], off);
  }
  uint4 sr = ((const uint4*)(t + (size_t)v*64))[q];       // self row (L2-hot)
  acc[0] += bfl(sr.x); acc[1] += bfh(sr.x); acc[2] += bfl(sr.y); acc[3] += bfh(sr.y);
  acc[4] += bfl(sr.z); acc[5] += bfh(sr.z); acc[6] += bfl(sr.w); acc[7] += bfh(sr.w);
  float dv = rsqrtf((float)(cn + 1));
  float4 b0 = ((const float4*)b)[2*q], b1 = ((const float4*)b)[2*q+1];
  if (lane < 8){
    float4 r0, r1;
    r0.x = fmaxf(fmaf(acc[0], dv, b0.x), 0.f); r0.y = fmaxf(fmaf(acc[1], dv, b0.y), 0.f);
    r0.z = fmaxf(fmaf(acc[2], dv, b0.z), 0.f); r0.w = fmaxf(fmaf(acc[3], dv, b0.w), 0.f);
    r1.x = fmaxf(fmaf(acc[4], dv, b1.x), 0.f); r1.y = fmaxf(fmaf(acc[5], dv, b1.y), 0.f);
    r1.z = fmaxf(fmaf(acc[6], dv, b1.z), 0.f); r1.w = fmaxf(fmaf(acc[7], dv, b1.w), 0.f);
    ((float4*)(h + (size_t)v*64))[2*q]   = r0;            // 256B store
    ((float4*)(h + (size_t)v*64))[2*q+1] = r1;
  }
}

// GAT agg, bf16 rows: softmax over in-edges + analytic self term, then
// 8-rows-per-instruction weighted gather.
__global__ __launch_bounds__(256) void k_gat_agg(const unsigned short* __restrict__ t,
                          const int* __restrict__ adj, const int* __restrict__ cnt,
                          const float* __restrict__ als, const float* __restrict__ ald,
                          const float* __restrict__ b, float* __restrict__ h, int n){
  int lane = threadIdx.x & 63;
  int v = blockIdx.x*4 + uwave();
  if (v >= n) return;
  int c = min(cnt[v], CAP);
  const int* row = adj + (size_t)v*CAP;
  int ureg = n;                               // pad -> zero row for gather
  if (lane < c) ureg = row[lane];
  int usafe = (lane < c) ? ureg : v;
  float adv = ald[v];                         // uniform
  float e = als[usafe] + adv;                 // 4B gather (lane=edge)
  e = e > 0.f ? e : 0.2f*e;
  float es = als[v] + adv;                    // self score (uniform)
  es = es > 0.f ? es : 0.2f*es;
  float em = (lane < c) ? e : -1e30f;
  #pragma unroll
  for (int off = 32; off; off >>= 1) em = fmaxf(em, __shfl_xor(em, off));
  em = fmaxf(em, es);
  float p = (lane < c) ? __expf(e - em) : 0.f;
  float s = p;
  #pragma unroll
  for (int off = 32; off; off >>= 1) s += __shfl_xor(s, off);
  float ps = __expf(es - em);
  float inv = 1.f / (s + ps);
  int g = lane >> 3, q = lane & 7;
  float acc[8] = {0.f,0.f,0.f,0.f,0.f,0.f,0.f,0.f};
  int iters = (c + 7) >> 3;
  for (int jj = 0; jj < iters; jj++){
    int   u = __shfl(ureg, jj*8 + g);
    float w = __shfl(p,    jj*8 + g);         // pad slots p=0
    uint4 r = ((const uint4*)(t + (size_t)u*64))[q];
    acc[0] = fmaf(w, bfl(r.x), acc[0]); acc[1] = fmaf(w, bfh(r.x), acc[1]);
    acc[2] = fmaf(w, bfl(r.y), acc[2]); acc[3] = fmaf(w, bfh(r.y), acc[3]);
    acc[4] = fmaf(w, bfl(r.z), acc[4]); acc[5] = fmaf(w, bfh(r.z), acc[5]);
    acc[6] = fmaf(w, bfl(r.w), acc[6]); acc[7] = fmaf(w, bfh(r.w), acc[7]);
  }
  #pragma unroll
  for (int off = 8; off <= 32; off <<= 1){
    #pragma unroll
    for (int k = 0; k < 8; k++) acc[k] += __shfl_xor(acc[k], off);
  }
  uint4 sr = ((const uint4*)(t + (size_t)v*64))[q];       // self row
  acc[0] = fmaf(ps, bfl(sr.x), acc[0]); acc[1] = fmaf(ps, bfh(sr.x), acc[1]);
  acc[2] = fmaf(ps, bfl(sr.y), acc[2]); acc[3] = fmaf(ps, bfh(sr.y), acc[3]);
  acc[4] = fmaf(ps, bfl(sr.z), acc[4]); acc[5] = fmaf(ps, bfh(sr.z), acc[5]);
  acc[6] = fmaf(ps, bfl(sr.w), acc[6]); acc[7] = fmaf(ps, bfh(sr.w), acc[7]);
  float4 b0 = ((const float4*)b)[2*q], b1 = ((const float4*)b)[2*q+1];
  if (lane < 8){
    float4 r0, r1;
    r0.x = fmaxf(fmaf(acc[0], inv, b0.x), 0.f); r0.y = fmaxf(fmaf(acc[1], inv, b0.y), 0.f);
    r0.z = fmaxf(fmaf(acc[2], inv, b0.z), 0.f); r0.w = fmaxf(fmaf(acc[3], inv, b0.w), 0.f);
    r1.x = fmaxf(fmaf(acc[4], inv, b1.x), 0.f); r1.y = fmaxf(fmaf(acc[5], inv, b1.y), 0.f);
    r1.z = fmaxf(fmaf(acc[6], inv, b1.z), 0.f); r1.w = fmaxf(fmaf(acc[7], inv, b1.w), 0.f);
    ((float4*)(h + (size_t)v*64))[2*q]   = r0;
    ((float4*)(h + (size_t)v*64))[2*q+1] = r1;
  }
}

// heads + mean: weights from GLOBAL into VGPRs (no LDS demotion), block
// feature-sums atomicAdd'ed to emb_acc[64].
__global__ __launch_bounds__(256, 4) void k_heads(const float* __restrict__ h,
                        const float* __restrict__ Wopt, const float* __restrict__ bopt,
                        const float* __restrict__ Wb1, const float* __restrict__ bb1,
                        const float* __restrict__ Wb2, const float* __restrict__ bb2,
                        float* __restrict__ out_opt, float* __restrict__ out_bot,
                        float* __restrict__ emb_acc, int n){
  __shared__ float red[256];
  int tid = threadIdx.x;
  int lane = tid & 63;
  float wreg[64];
  #pragma unroll
  for (int f = 0; f < 64; f++){
    float w = 0.f;
    if (lane < 10)       w = Wopt[f*10 + lane];
    else if (lane >= 32) w = Wb1[f*32 + (lane-32)];
    wreg[f] = w;                               // strided global, once per wave
  }
  float bcr = 0.f;
  if (lane < 10)       bcr = bopt[lane];
  else if (lane >= 32) bcr = bb1[lane-32];
  float wb2r = (lane >= 32) ? Wb2[lane-32] : 0.f;
  float bb2r = bb2[0];
  int gw = blockIdx.x*4 + uwave();
  int nw = gridDim.x*4;
  float gacc = 0.f;
  for (int v = gw; v < n; v += nw){
    const float4* hr = (const float4*)(h + (size_t)v*64);
    float acc = bcr;
    #pragma unroll
    for (int f4 = 0; f4 < 16; f4++){
      float4 hv = hr[f4];
      acc = fmaf(hv.x, wreg[f4*4+0], acc);
      acc = fmaf(hv.y, wreg[f4*4+1], acc);
      acc = fmaf(hv.z, wreg[f4*4+2], acc);
      acc = fmaf(hv.w, wreg[f4*4+3], acc);
    }
    gacc += h[(size_t)v*64 + lane];           // coalesced, L2-hot
    if (lane < 10) out_opt[(size_t)v*10 + lane] = acc;
    float contrib = (lane >= 32) ? fmaxf(acc, 0.f) * wb2r : 0.f;
    #pragma unroll
    for (int off = 32; off; off >>= 1) contrib += __shfl_xor(contrib, off);
    if (lane == 0) out_bot[v] = 1.f / (1.f + __expf(-(contrib + bb2r)));
  }
  red[tid] = gacc;
  __syncthreads();
  if (tid < 64)
    atomicAdd(&emb_acc[tid], red[tid] + red[64+tid] + red[128+tid] + red[192+tid]);
}

__global__ void k_embed(const float* __restrict__ emb_acc, float* __restrict__ out_emb,
                        float invn){
  if (threadIdx.x < 64) out_emb[threadIdx.x] = emb_acc[threadIdx.x] * invn;
}

extern "C" void kernel_launch(void* const* d_in, const int* in_sizes, int n_in,
                              void* d_out, int out_size, void* d_ws, size_t ws_size,
                              hipStream_t stream) {
  const float* x    = (const float*)d_in[0];
  const int*   ei   = (const int*)d_in[1];
  const float* W1   = (const float*)d_in[2];
  const float* b1   = (const float*)d_in[3];
  const float* W2   = (const float*)d_in[4];
  const float* a_s  = (const float*)d_in[5];
  const float* a_d  = (const float*)d_in[6];
  const float* b2   = (const float*)d_in[7];
  const float* W3   = (const float*)d_in[8];
  const float* b3   = (const float*)d_in[9];
  const float* Wopt = (const float*)d_in[10];
  const float* bopt = (const float*)d_in[11];
  const float* Wb1  = (const float*)d_in[12];
  const float* bb1  = (const float*)d_in[13];
  const float* Wb2  = (const float*)d_in[14];
  const float* bb2  = (const float*)d_in[15];

  int n = in_sizes[0] / 32;      // 100000
  int e = in_sizes[1] / 2;       // 1250000
  const int* src = ei;
  const int* dst = ei + e;

  char* ws = (char*)d_ws;
  size_t off = 0;
  auto alloc = [&](size_t bytes) -> void* {
    void* p = ws + off;
    off += (bytes + 255) & ~(size_t)255;
    return p;
  };
  int*            cnt     = (int*)           alloc((size_t)n * 4);
  int*            adj     = (int*)           alloc((size_t)n * CAP * 4);
  float*          als     = (float*)         alloc((size_t)n * 4);
  float*          ald     = (float*)         alloc((size_t)n * 4);
  unsigned short* xh      = (unsigned short*)alloc((size_t)n * 32 * 2);
  unsigned short* tb      = (unsigned short*)alloc((size_t)(n+1) * 64 * 2); // +zero row n
  float*          hbuf    = (float*)         alloc((size_t)n * 64 * 4);
  float*          emb_acc = (float*)         alloc((size_t)64 * 4);
  float*          y1      = (float*)tb;      // alias: y1 dead before t2 written

  float* out_opt = (float*)d_out;
  float* out_bot = out_opt + (size_t)n * 10;
  float* out_emb = out_bot + n;

  int nbN  = (n + 255) / 256;
  int nbE  = (e + 255) / 256;
  int nb4  = (n + 3) / 4;
  int nper = (n + 7) / 8;
  int nc4  = (n*32/4 + 255) / 256;

  k_init<<<nbN, 256, 0, stream>>>(cnt, tb, emb_acc, n);
  k_cast<<<nc4, 256, 0, stream>>>(x, xh, n*32/4);
  k_hist<<<nbE*8, 256, 0, stream>>>(src, dst, cnt, adj, e, nper);

  // layer 1: GCN(32->64): aggregate bf16 x rows -> y1, gemm + bias+relu -> h1
  k_agg32<<<nb4, 256, 0, stream>>>(xh, adj, cnt, y1, n);
  k_gemm<32, false, true><<<1024, 256, 0, stream>>>(y1, W1, cnt, b1, hbuf, n);

  // layer 2: GAT(64->64): gemm -> bf16 t2 + scores, softmax-gather -> h2
  k_gemm_alpha<<<1024, 256, 0, stream>>>(hbuf, W2, a_s, a_d, tb, als, ald, n);
  k_gat_agg<<<nb4, 256, 0, stream>>>(tb, adj, cnt, als, ald, b2, hbuf, n);

  // layer 3: GCN(64->64): gemm (pre-scaled) -> bf16 t3, gather -> h3
  k_gemm_b<true><<<1024, 256, 0, stream>>>(hbuf, W3, cnt, tb, n);
  k_gcn_agg<<<nb4, 256, 0, stream>>>(tb, adj, cnt, b3, hbuf, n);

  // heads (+ mean via 64-address device atomics), then trivial scale
  k_heads<<<1024, 256, 0, stream>>>(hbuf, Wopt, bopt, Wb1, bb1, Wb2, bb2,
                                    out_opt, out_bot, emb_acc, n);
  k_embed<<<1, 64, 0, stream>>>(emb_acc, out_emb, 1.0f / (float)n);
}